// Round 17
// baseline (765.296 us; speedup 1.0000x reference)
//
#include <hip/hip_runtime.h>
#include <hip/hip_bf16.h>
#include <math.h>

#define D 128
#define DD 16384
#define NEMAX 96
typedef unsigned short u16;
typedef __attribute__((ext_vector_type(8))) short short8v;
typedef __attribute__((ext_vector_type(4))) short short4v;
typedef __attribute__((ext_vector_type(4))) float f32x4;

__device__ __forceinline__ u16 f2s(float v){
    union { __hip_bfloat16 h; u16 u; } c; c.h = __float2bfloat16(v); return c.u;
}
__device__ __forceinline__ float s2f(u16 u){
    union { __hip_bfloat16 h; u16 u; } c; c.u = u; return __bfloat162float(c.h);
}
__device__ __forceinline__ float lrelu(float x){ return x > 0.f ? x : 0.2f*x; }

// ---------------- small utility kernels ----------------
__global__ void k_prepz(int* __restrict__ zz, int zw, int* __restrict__ nstart,
                        int* __restrict__ nend, int nb){
    int i = blockIdx.x*blockDim.x + threadIdx.x;
    int stride = gridDim.x*blockDim.x;
    for (int k = i; k < zw; k += stride) zz[k] = 0;
    for (int k = i; k < nb; k += stride){ nstart[k] = 0x7fffffff; nend[k] = -1; }
}
__global__ void k_f2b4(const float* __restrict__ in, u16* __restrict__ out, int n4){
    for (int i = blockIdx.x*blockDim.x + threadIdx.x; i < n4; i += gridDim.x*blockDim.x){
        float4 a = ((const float4*)in)[i];
        short4v pk;
        pk[0] = (short)f2s(a.x); pk[1] = (short)f2s(a.y);
        pk[2] = (short)f2s(a.z); pk[3] = (short)f2s(a.w);
        *(short4v*)(out + (size_t)i*4) = pk;
    }
}
__global__ void k_ideg(const int* __restrict__ row, int* __restrict__ deg, int E_){
    for (int i = blockIdx.x*blockDim.x + threadIdx.x; i < E_; i += gridDim.x*blockDim.x)
        atomicAdd(&deg[row[i]], 1);
}
__global__ void k_scan1(const int* __restrict__ ideg, int* __restrict__ rowptr,
                        int* __restrict__ bsum, int n){
    __shared__ int buf[256];
    int t = threadIdx.x, i = blockIdx.x*256 + t;
    int v = (i < n) ? ideg[i] : 0;
    buf[t] = v;
    __syncthreads();
    #pragma unroll
    for (int o = 1; o < 256; o <<= 1){
        int u = (t >= o) ? buf[t-o] : 0;
        __syncthreads();
        buf[t] += u;
        __syncthreads();
    }
    if (i < n) rowptr[i] = buf[t] - v;
    if (t == 255) bsum[blockIdx.x] = buf[255];
}
__global__ void k_scan2(int* __restrict__ bsum, int nb){
    __shared__ int buf[256];
    __shared__ int carry_s;
    int t = threadIdx.x;
    if (t == 0) carry_s = 0;
    __syncthreads();
    for (int base = 0; base < nb; base += 256){
        int v = (base + t < nb) ? bsum[base + t] : 0;
        buf[t] = v;
        __syncthreads();
        #pragma unroll
        for (int o = 1; o < 256; o <<= 1){
            int u = (t >= o) ? buf[t-o] : 0;
            __syncthreads();
            buf[t] += u;
            __syncthreads();
        }
        if (base + t < nb) bsum[base + t] = carry_s + buf[t] - v;
        int last = buf[255];
        __syncthreads();
        if (t == 0) carry_s += last;
        __syncthreads();
    }
}
__global__ void k_scan3(int* __restrict__ rowptr, const int* __restrict__ bsum,
                        const int* __restrict__ ideg, int* __restrict__ nstart,
                        int* __restrict__ nend, int n, int E_){
    int i = blockIdx.x*blockDim.x + threadIdx.x;
    if (i < n){
        int rpi = rowptr[i] + bsum[i >> 8];
        rowptr[i] = rpi;
        if (i == 0) rowptr[n] = E_;
        if (ideg[i] > 0){
            int b = rpi >> 6;
            atomicMin(&nstart[b], i);
            atomicMax(&nend[b], i);
        }
    }
}
__global__ void k_scatter(const int* __restrict__ row, const int* __restrict__ col,
                          const int* __restrict__ ety, const int* __restrict__ rowptr,
                          int* __restrict__ cnt, unsigned* __restrict__ jk, int E_){
    for (int e = blockIdx.x*blockDim.x + threadIdx.x; e < E_; e += gridDim.x*blockDim.x){
        int i = row[e];
        int pos = rowptr[i] + atomicAdd(&cnt[i], 1);
        jk[pos] = ((unsigned)col[e] & 0xFFFFu) | ((unsigned)ety[e] << 16);
    }
}
__global__ void k_bnapply(const u16* __restrict__ acc, const float* __restrict__ gp,
                          float inv_ne, int n, u16* __restrict__ dstb,
                          float* __restrict__ dstf){
    int d = threadIdx.x & 127;
    float m = gp[d] * inv_ne;
    float var = gp[128 + d] * inv_ne - m*m;
    float sc = rsqrtf(var + 1e-5f);
    for (int i = blockIdx.x*blockDim.x + threadIdx.x; i < n; i += gridDim.x*blockDim.x){
        float v = s2f(acc[i]) * 0.5f;
        float r = tanhf((v - m) * sc);
        dstb[i] = f2s(r);
        if (dstf) dstf[i] = r;
    }
}
__global__ void k_bnapply2(const u16* __restrict__ acc0, const float* __restrict__ gp0,
                           u16* __restrict__ d0b,
                           const u16* __restrict__ acc1, const float* __restrict__ gp1,
                           u16* __restrict__ d1b, float* __restrict__ d1f,
                           float inv_ne, int n, int gb){
    int pb = blockIdx.x >= gb;
    const u16* acc = pb ? acc1 : acc0;
    const float* gp = pb ? gp1 : gp0;
    u16* db = pb ? d1b : d0b;
    float* df = pb ? d1f : nullptr;
    int b = blockIdx.x - (pb ? gb : 0);
    int d = threadIdx.x & 127;
    float m = gp[d] * inv_ne;
    float var = gp[128 + d] * inv_ne - m*m;
    float sc = rsqrtf(var + 1e-5f);
    for (int i = b*blockDim.x + threadIdx.x; i < n; i += gb*blockDim.x){
        float v = s2f(acc[i]) * 0.5f;
        float r = tanhf((v - m) * sc);
        db[i] = f2s(r);
        if (df) df[i] = r;
    }
}

// ---------------- batched relation prep ----------------
__global__ void k_relprep(const float* __restrict__ rel_comp, const float* __restrict__ rel_info,
        const float* __restrict__ rl11, const float* __restrict__ rl12,
        const float* __restrict__ rl11a, const float* __restrict__ rl12a,
        const float* __restrict__ cloop, const float* __restrict__ cw1,
        const float* __restrict__ cw2, float* __restrict__ pr1out,
        float* __restrict__ rel2all, int NR){
    int b = blockIdx.x, t = threadIdx.x;
    __shared__ float v[D];
    __shared__ float h[D];
    if (b < NR){
        v[t] = rel_comp[(size_t)b*D + t];
        __syncthreads();
        float a = 0.f;
        #pragma unroll 8
        for (int k = 0; k < D; k++) a += v[k] * rl11[(size_t)k*D + t];
        h[t] = lrelu(a);
        __syncthreads();
        float o = 0.f;
        #pragma unroll 8
        for (int k = 0; k < D; k++) o += h[k] * rl12[(size_t)k*D + t];
        pr1out[(size_t)b*D + t] = o;
        return;
    }
    int bb = b - NR;
    int l = bb / (NR+1), r = bb - l*(NR+1);
    float xv;
    if (r == NR)      xv = cloop[l*D + t];
    else if (l == 1)  xv = rel_comp[(size_t)r*D + t];
    else              xv = rel_info[(size_t)r*D + t];
    v[t] = xv;
    __syncthreads();
    if (l == 2 && r < NR){
        float a = 0.f;
        #pragma unroll 8
        for (int k = 0; k < D; k++) a += v[k] * rl11a[(size_t)k*D + t];
        h[t] = lrelu(a);
        __syncthreads();
        float o = 0.f;
        #pragma unroll 8
        for (int k = 0; k < D; k++) o += h[k] * rl12a[(size_t)k*D + t];
        v[t] = o;
        __syncthreads();
    }
    const float* w1 = cw1 + (size_t)l*DD;
    const float* w2 = cw2 + (size_t)l*DD;
    float a = 0.f;
    #pragma unroll 8
    for (int k = 0; k < D; k++) a += v[k] * w1[(size_t)k*D + t];
    h[t] = lrelu(a);
    __syncthreads();
    float o = 0.f;
    #pragma unroll 8
    for (int k = 0; k < D; k++) o += h[k] * w2[(size_t)k*D + t];
    rel2all[((size_t)l*(NR+1) + r)*D + t] = o;
}

// ---------------- weight prep ----------------
struct TEnt { const float* s; u16* d; int ldd; };
struct TTab { TEnt e[18]; };
__global__ void k_wprep(TTab tab){
    TEnt en = tab.e[blockIdx.x];
    int t = threadIdx.x;
    int n = t >> 1, h = t & 1;
    #pragma unroll
    for (int g = 0; g < 8; ++g){
        int k0 = h*64 + g*8;
        short8v pk;
        #pragma unroll
        for (int q = 0; q < 8; ++q) pk[q] = (short)f2s(en.s[(size_t)(k0+q)*D + n]);
        *(short8v*)(en.d + (size_t)n*en.ldd + k0) = pk;
    }
}

// ---------------- MFMA row GEMM (MLPs + final) ----------------
struct Srcs { const void* p0; const void* p1; const void* p2; int f0, f1, f2; };

template<int NSEG, int EPI, bool RSN>
__global__ __launch_bounds__(256) void k_mrow(Srcs S, const u16* __restrict__ WT,
        void* __restrict__ out, int NE_){
    __shared__ __align__(16) short As[128*128];
    int tid = threadIdx.x;
    int row0 = blockIdx.x * 128;
    int lane = tid & 63, w = tid >> 6;
    int l15 = lane & 15, lq = lane >> 4;
    int nhalf = w & 1, mquad = w >> 1;
    f32x4 acc[4][4];
    #pragma unroll
    for (int a = 0; a < 4; a++)
        #pragma unroll
        for (int b = 0; b < 4; b++) acc[a][b] = (f32x4){0.f,0.f,0.f,0.f};

    int sr = tid >> 1, sh = tid & 1;
    int rr = row0 + sr; if (rr >= NE_) rr = NE_ - 1;

    #pragma unroll
    for (int s = 0; s < NSEG; ++s){
        const void* sp = (s == 0) ? S.p0 : (s == 1) ? S.p1 : S.p2;
        int sf = (s == 0) ? S.f0 : (s == 1) ? S.f1 : S.f2;
        if (s) __syncthreads();
        #pragma unroll
        for (int g = 0; g < 8; ++g){
            int k8 = sh*64 + g*8;
            short8v pk;
            if (sf){
                const float* fp = (const float*)sp + (size_t)rr*D + k8;
                #pragma unroll
                for (int q = 0; q < 8; ++q) pk[q] = (short)f2s(fp[q]);
            } else {
                pk = *(const short8v*)((const u16*)sp + (size_t)rr*D + k8);
            }
            *(short8v*)(As + sr*D + (((k8>>3) ^ (sr&7))<<3)) = pk;
        }
        if (RSN && s == 0){
            float ss = 0.f;
            #pragma unroll
            for (int g = 0; g < 8; ++g){
                int k8 = sh*64 + g*8;
                short8v v = *(const short8v*)(As + sr*D + (((k8>>3) ^ (sr&7))<<3));
                #pragma unroll
                for (int q = 0; q < 8; ++q){ float f = s2f((u16)v[q]); ss += f*f; }
            }
            ss += __shfl_xor(ss, 1, 64);
            float rsc = 1.f / fmaxf(sqrtf(ss), 1e-12f);
            #pragma unroll
            for (int g = 0; g < 8; ++g){
                int k8 = sh*64 + g*8;
                short* ap = As + sr*D + (((k8>>3) ^ (sr&7))<<3);
                short8v v = *(const short8v*)ap;
                short8v pk;
                #pragma unroll
                for (int q = 0; q < 8; ++q) pk[q] = (short)f2s(s2f((u16)v[q]) * rsc);
                *(short8v*)ap = pk;
            }
        }
        __syncthreads();
        short8v bfr[4][4];
        #pragma unroll
        for (int nt = 0; nt < 4; ++nt)
            #pragma unroll
            for (int kk = 0; kk < 4; ++kk){
                size_t idx = (size_t)(nhalf*64 + nt*16 + l15)*(NSEG*D) + (size_t)s*D + kk*32 + lq*8;
                bfr[nt][kk] = *(const short8v*)(WT + idx);
            }
        #pragma unroll
        for (int mt = 0; mt < 4; ++mt){
            int ar = mquad*64 + mt*16 + l15;
            short8v afr[4];
            #pragma unroll
            for (int kk = 0; kk < 4; ++kk)
                afr[kk] = *(const short8v*)(As + ar*D + (((kk*4 + lq) ^ (ar&7))<<3));
            #pragma unroll
            for (int nt = 0; nt < 4; ++nt)
                #pragma unroll
                for (int kk = 0; kk < 4; ++kk)
                    acc[mt][nt] = __builtin_amdgcn_mfma_f32_16x16x32_bf16(
                        afr[kk], bfr[nt][kk], acc[mt][nt], 0, 0, 0);
        }
    }
    #pragma unroll
    for (int mt = 0; mt < 4; ++mt){
        #pragma unroll
        for (int nt = 0; nt < 4; ++nt){
            #pragma unroll
            for (int r = 0; r < 4; ++r){
                int gr = row0 + mquad*64 + mt*16 + lq*4 + r;
                if (gr >= NE_) continue;
                int c = nhalf*64 + nt*16 + l15;
                float v = acc[mt][nt][r];
                if (EPI == 0) ((float*)out)[(size_t)gr*D + c] = v;
                else ((u16*)out)[(size_t)gr*D + c] = f2s(EPI == 2 ? lrelu(v) : v);
            }
        }
    }
}

// ---------------- conv GEMM, two-problem capable ----------------
struct ConvP { const u16* x; const u16* WT; u16* out; u16* ub; const float* loop; float* gp; };

template<int MODE>
__global__ __launch_bounds__(256) void k_mrow2(ConvP A, ConvP B, int rb, int NE_){
    __shared__ __align__(16) short As[128*128];
    int pb = blockIdx.x >= rb;
    ConvP P = pb ? B : A;
    int row0 = (blockIdx.x - (pb ? rb : 0)) * 128;
    int tid = threadIdx.x;
    int lane = tid & 63, w = tid >> 6;
    int l15 = lane & 15, lq = lane >> 4;
    int nhalf = w & 1, mquad = w >> 1;
    f32x4 acc[4][4];
    #pragma unroll
    for (int a = 0; a < 4; a++)
        #pragma unroll
        for (int b = 0; b < 4; b++) acc[a][b] = (f32x4){0.f,0.f,0.f,0.f};

    int sr = tid >> 1, sh = tid & 1;
    int rr = row0 + sr; if (rr >= NE_) rr = NE_ - 1;
    #pragma unroll
    for (int g = 0; g < 8; ++g){
        int k8 = sh*64 + g*8;
        short8v pk = *(const short8v*)(P.x + (size_t)rr*D + k8);
        *(short8v*)(As + sr*D + (((k8>>3) ^ (sr&7))<<3)) = pk;
    }
    __syncthreads();
    short8v bfr[4][4];
    #pragma unroll
    for (int nt = 0; nt < 4; ++nt)
        #pragma unroll
        for (int kk = 0; kk < 4; ++kk)
            bfr[nt][kk] = *(const short8v*)(P.WT + (size_t)(nhalf*64 + nt*16 + l15)*D + kk*32 + lq*8);
    #pragma unroll
    for (int mt = 0; mt < 4; ++mt){
        int ar = mquad*64 + mt*16 + l15;
        short8v afr[4];
        #pragma unroll
        for (int kk = 0; kk < 4; ++kk)
            afr[kk] = *(const short8v*)(As + ar*D + (((kk*4 + lq) ^ (ar&7))<<3));
        #pragma unroll
        for (int nt = 0; nt < 4; ++nt)
            #pragma unroll
            for (int kk = 0; kk < 4; ++kk)
                acc[mt][nt] = __builtin_amdgcn_mfma_f32_16x16x32_bf16(
                    afr[kk], bfr[nt][kk], acc[mt][nt], 0, 0, 0);
    }
    if (MODE == 3){
        float cs[4] = {0,0,0,0}, cs2[4] = {0,0,0,0};
        #pragma unroll
        for (int mt = 0; mt < 4; ++mt)
            #pragma unroll
            for (int nt = 0; nt < 4; ++nt)
                #pragma unroll
                for (int r = 0; r < 4; ++r){
                    int gr = row0 + mquad*64 + mt*16 + lq*4 + r;
                    if (gr >= NE_) continue;
                    int c = nhalf*64 + nt*16 + l15;
                    float v = acc[mt][nt][r];
                    P.out[(size_t)gr*D + c] = f2s(v);
                    float h = v * 0.5f;
                    cs[nt] += h; cs2[nt] += h*h;
                }
        __syncthreads();
        float* ps  = (float*)As;
        float* ps2 = ps + 1024;
        int slot = mquad*4 + lq;
        #pragma unroll
        for (int nt = 0; nt < 4; ++nt){
            int c = nhalf*64 + nt*16 + l15;
            ps[slot*128 + c]  = cs[nt];
            ps2[slot*128 + c] = cs2[nt];
        }
        __syncthreads();
        if (tid < 128){
            float s = 0.f, s2 = 0.f;
            #pragma unroll
            for (int q = 0; q < 8; ++q){ s += ps[q*128 + tid]; s2 += ps2[q*128 + tid]; }
            atomicAdd(&P.gp[tid], s);
            atomicAdd(&P.gp[128 + tid], s2);
        }
    } else {
        #pragma unroll
        for (int mt = 0; mt < 4; ++mt)
            #pragma unroll
            for (int nt = 0; nt < 4; ++nt)
                #pragma unroll
                for (int r = 0; r < 4; ++r){
                    int gr = row0 + mquad*64 + mt*16 + lq*4 + r;
                    if (gr >= NE_) continue;
                    int c = nhalf*64 + nt*16 + l15;
                    P.out[(size_t)gr*D + c] = f2s(acc[mt][nt][r]);
                }
        for (int idx = tid; idx < 128*128; idx += 256){
            int r2 = idx >> 7, c = idx & 127;
            int gr = row0 + r2;
            if (gr < NE_){
                float v = s2f((u16)As[r2*D + ((((c>>3) ^ (r2&7))<<3) | (c&7))]) * P.loop[c];
                P.ub[(size_t)gr*D + c] = f2s(v);
            }
        }
    }
}

// ---------------- fused edge kernel, two-problem capable ----------------
struct FP { const u16* x; const float* rel2; const u16* xattb; const u16* WT;
            const float* aatt; const float* loop; u16* u; };

__global__ __launch_bounds__(256) void k_fedge(
        const unsigned* __restrict__ jk,
        const int* __restrict__ rowptr,
        const int* __restrict__ nstart, const int* __restrict__ nend,
        FP fa, FP fb, int nb){
    __shared__ __align__(16) short As[NEMAX*D];
    __shared__ u16 jL[NEMAX], kL[NEMAX], iL[NEMAX];
    __shared__ float sc[NEMAX];
    __shared__ float red[2][NEMAX];
    int pb = blockIdx.x >= nb;
    FP P = pb ? fb : fa;
    int b = blockIdx.x - (pb ? nb : 0);
    int ns = nstart[b];
    if (ns == 0x7fffffff) return;
    int nn = nend[b] - ns + 1;
    int tid = threadIdx.x;
    int estart = rowptr[ns];
    int ne = rowptr[ns + nn] - estart;
    if (ne > NEMAX) ne = NEMAX;
    int T = (ne + 15) >> 4;
    int nrows = T << 4;
    if (tid < ne){
        unsigned v = jk[estart + tid];
        jL[tid] = (u16)(v & 0xFFFFu); kL[tid] = (u16)(v >> 16);
    }
    if (tid < nn){
        int i = ns + tid;
        int s0 = rowptr[i] - estart, s1 = rowptr[i+1] - estart;
        if (s0 < 0) s0 = 0;
        if (s1 > NEMAX) s1 = NEMAX;
        for (int p = s0; p < s1; ++p) iL[p] = (u16)i;
    }
    __syncthreads();
    for (int it = tid; it < nrows*4; it += 256){
        int p = it >> 2, part = it & 3;
        int ps = (p < ne) ? p : (ne - 1);
        int j = jL[ps], krel = kL[ps];
        #pragma unroll
        for (int g = 0; g < 4; ++g){
            int k8 = part*32 + g*8;
            short8v sv = *(const short8v*)(P.x + (size_t)j*D + k8);
            const float* rp = P.rel2 + (size_t)krel*D + k8;
            short8v pk;
            #pragma unroll
            for (int q = 0; q < 8; ++q) pk[q] = (short)f2s(s2f((u16)sv[q]) * rp[q]);
            *(short8v*)(As + p*D + (((k8>>3) ^ (p&7))<<3)) = pk;
        }
    }
    __syncthreads();
    int lane = tid & 63, w = tid >> 6;
    int l15 = lane & 15, lq = lane >> 4;
    int nhalf = w & 1, mq = w >> 1;
    short8v bfr[4][4];
    #pragma unroll
    for (int nt = 0; nt < 4; ++nt)
        #pragma unroll
        for (int kk = 0; kk < 4; ++kk)
            bfr[nt][kk] = *(const short8v*)(P.WT + (size_t)(nhalf*64 + nt*16 + l15)*D + kk*32 + lq*8);
    float av[4];
    #pragma unroll
    for (int nt = 0; nt < 4; ++nt) av[nt] = P.aatt[nhalf*64 + nt*16 + l15];

    // preload xatt addends for ALL of this wave-pair's tiles (T<=6 -> <=3 tiles)
    float xvA[3][4][4];
    #pragma unroll
    for (int tt = 0; tt < 3; ++tt){
        int t = mq + 2*tt;
        if (t < T){
            #pragma unroll
            for (int r = 0; r < 4; ++r){
                int el = t*16 + lq*4 + r;
                int ep = (el < ne) ? el : (ne - 1);
                int ii = iL[ep];
                #pragma unroll
                for (int nt = 0; nt < 4; ++nt)
                    xvA[tt][r][nt] = s2f(P.xattb[(size_t)ii*D + nhalf*64 + nt*16 + l15]);
            }
        }
    }
    #pragma unroll
    for (int tt = 0; tt < 3; ++tt){
        int t = mq + 2*tt;
        if (t >= T) break;
        int ar = t*16 + l15;
        short8v afr[4];
        #pragma unroll
        for (int kk = 0; kk < 4; ++kk)
            afr[kk] = *(const short8v*)(As + ar*D + (((kk*4 + lq) ^ (ar&7))<<3));
        f32x4 acc[4];
        #pragma unroll
        for (int nt = 0; nt < 4; ++nt) acc[nt] = (f32x4){0.f,0.f,0.f,0.f};
        #pragma unroll
        for (int nt = 0; nt < 4; ++nt)
            #pragma unroll
            for (int kk = 0; kk < 4; ++kk)
                acc[nt] = __builtin_amdgcn_mfma_f32_16x16x32_bf16(
                    afr[kk], bfr[nt][kk], acc[nt], 0, 0, 0);
        #pragma unroll
        for (int r = 0; r < 4; ++r){
            int el = t*16 + lq*4 + r;
            float p = 0.f;
            if (el < ne){
                #pragma unroll
                for (int nt = 0; nt < 4; ++nt)
                    p += lrelu(acc[nt][r] + xvA[tt][r][nt]) * av[nt];
            }
            p += __shfl_xor(p, 1, 64);
            p += __shfl_xor(p, 2, 64);
            p += __shfl_xor(p, 4, 64);
            p += __shfl_xor(p, 8, 64);
            if (l15 == 0 && el < NEMAX) red[nhalf][el] = p;
        }
    }
    __syncthreads();
    if (tid < ne) sc[tid] = expf(red[0][tid] + red[1][tid]);
    __syncthreads();
    if (tid < nn){
        int i = ns + tid;
        int s0 = rowptr[i] - estart, s1 = rowptr[i+1] - estart;
        if (s1 > NEMAX) s1 = NEMAX;
        if (s1 > s0){
            float sum = 0.f;
            for (int p = s0; p < s1; ++p) sum += sc[p];
            float coef = rsqrtf((float)(s1 - s0)) / (sum + 1e-16f);
            for (int p = s0; p < s1; ++p) sc[p] *= coef;
        }
    }
    __syncthreads();
    int c = tid & 127, nh = tid >> 7;
    float loopc = P.loop[c];
    for (int n = nh; n < nn; n += 2){
        int i = ns + n;
        int s0 = rowptr[i] - estart, s1 = rowptr[i+1] - estart;
        if (s1 > NEMAX) s1 = NEMAX;
        if (s1 <= s0) continue;
        float a = s2f(P.x[(size_t)i*D + c]) * loopc;
        int p = s0;
        for (; p + 4 <= s1; p += 4){
            float v0 = s2f((u16)As[(p+0)*D + ((((c>>3) ^ ((p+0)&7))<<3) | (c&7))]);
            float v1 = s2f((u16)As[(p+1)*D + ((((c>>3) ^ ((p+1)&7))<<3) | (c&7))]);
            float v2 = s2f((u16)As[(p+2)*D + ((((c>>3) ^ ((p+2)&7))<<3) | (c&7))]);
            float v3 = s2f((u16)As[(p+3)*D + ((((c>>3) ^ ((p+3)&7))<<3) | (c&7))]);
            a += sc[p]*v0 + sc[p+1]*v1 + sc[p+2]*v2 + sc[p+3]*v3;
        }
        for (; p < s1; ++p)
            a += sc[p] * s2f((u16)As[p*D + ((((c>>3) ^ (p&7))<<3) | (c&7))]);
        P.u[(size_t)i*D + c] = f2s(a);
    }
}

extern "C" void kernel_launch(void* const* d_in, const int* in_sizes, int n_in,
                              void* d_out, int out_size, void* d_ws, size_t ws_size,
                              hipStream_t stream){
    const int* eidx = (const int*)d_in[0];
    const int* ety  = (const int*)d_in[1];
    const float* ent_info = (const float*)d_in[2];
    const float* ent_comp = (const float*)d_in[3];
    const float* rel_comp = (const float*)d_in[4];
    const float* rel_info = (const float*)d_in[5];
    const float* al11 = (const float*)d_in[6],  *al12 = (const float*)d_in[7];
    const float* al21 = (const float*)d_in[8],  *al22 = (const float*)d_in[9];
    const float* rl11 = (const float*)d_in[10], *rl12 = (const float*)d_in[11];
    const float* rl11a = (const float*)d_in[12], *rl12a = (const float*)d_in[13];
    const float* allw = (const float*)d_in[14];
    const float* cw1 = (const float*)d_in[15], *cw2 = (const float*)d_in[16];
    const float* cgcn = (const float*)d_in[17], *cloop = (const float*)d_in[18];
    const float* cwatt = (const float*)d_in[19], *caatt = (const float*)d_in[20];

    const int E  = in_sizes[1];
    const int NE = in_sizes[2] / D;
    const int NR = in_sizes[4] / D;
    const int* row = eidx;
    const int* col = eidx + E;
    const size_t NEd = (size_t)NE * D;
    float* outp = (float*)d_out;
    const int NB64 = (E + 63) / 64;

    char* wsb = (char*)d_ws;
    size_t off = 0;
    auto takeB = [&](size_t bytes) -> void* {
        void* q = wsb + off;
        off = (off + bytes + 255) & ~(size_t)255;
        return q;
    };
    u16*   slotA = (u16*) takeB(NEd * 2);
    u16*   hb    = slotA;
    u16*   accB0 = slotA;
    u16*   xattb0= (u16*) takeB(NEd * 2);
    u16*   ub0   = (u16*) takeB(NEd * 2);
    u16*   e1b   = (u16*) takeB(NEd * 2);
    u16*   ao1b  = (u16*) takeB(NEd * 2);
    u16*   e2b   = (u16*) takeB(NEd * 2);
    u16*   cob   = (u16*) takeB(NEd * 2);
    float* rel2all = (float*)takeB((size_t)3*(NR+1)*D*4);
    int*   rowptr= (int*)  takeB((size_t)(NE+1)*4);
    unsigned* jk = (unsigned*)takeB((size_t)E*4);
    int*   bsum  = (int*)  takeB(1024*4);
    int*   nstart= (int*)  takeB((size_t)NB64*4);
    int*   nend  = (int*)  takeB((size_t)NB64*4);
    int ZW = 2*NE + 768;
    int*   zz    = (int*)  takeB((size_t)ZW*4);
    int*   ideg  = zz;
    int*   cnt   = zz + NE;
    float* gp3   = (float*)(zz + 2*NE);
    u16*   wtXatt = (u16*)takeB((size_t)3*DD*2);
    u16*   wtScore= (u16*)takeB((size_t)3*DD*2);
    u16*   wtGcn  = (u16*)takeB((size_t)3*DD*2);
    u16*   wtAl11 = (u16*)takeB((size_t)2*DD*2);
    u16*   wtAl12 = (u16*)takeB((size_t)DD*2);
    u16*   wtAl21 = (u16*)takeB((size_t)2*DD*2);
    u16*   wtAl22 = (u16*)takeB((size_t)DD*2);
    u16*   wtAllw = (u16*)takeB((size_t)3*DD*2);
    u16*   xcb   = e2b;

    size_t slab = ((NEd*2 + 255) & ~(size_t)255);
    bool wide = (off + 3*slab) <= ws_size;
    u16* xattb1 = wide ? (u16*)takeB(NEd * 2) : xattb0;
    u16* ub1    = wide ? (u16*)takeB(NEd * 2) : ub0;
    u16* accB1  = wide ? (u16*)takeB(NEd * 2) : accB0;

    const int GS = 2048, BS = 256;
    const int RB = (NE + 127) / 128;
    const int NB = (NE + 255) / 256;
    const float inv_ne = 1.f / (float)NE;

    TTab tab;
    int ti = 0;
    for (int l = 0; l < 3; ++l){
        tab.e[ti++] = { cwatt + (size_t)l*2*DD,        wtXatt  + (size_t)l*DD, 128 };
        tab.e[ti++] = { cwatt + (size_t)l*2*DD + DD,   wtScore + (size_t)l*DD, 128 };
        tab.e[ti++] = { cgcn  + (size_t)l*DD,          wtGcn   + (size_t)l*DD, 128 };
    }
    tab.e[ti++] = { al11,       wtAl11,        256 };
    tab.e[ti++] = { al11 + DD,  wtAl11 + 128,  256 };
    tab.e[ti++] = { al12,       wtAl12,        128 };
    tab.e[ti++] = { al21,       wtAl21,        256 };
    tab.e[ti++] = { al21 + DD,  wtAl21 + 128,  256 };
    tab.e[ti++] = { al22,       wtAl22,        128 };
    tab.e[ti++] = { allw,            wtAllw,        384 };
    tab.e[ti++] = { allw + DD,       wtAllw + 128,  384 };
    tab.e[ti++] = { allw + 2*DD,     wtAllw + 256,  384 };
    k_wprep<<<18, 256, 0, stream>>>(tab);

    k_prepz<<<256, BS, 0, stream>>>(zz, ZW, nstart, nend, NB64);
    k_f2b4<<<GS, BS, 0, stream>>>(ent_comp, xcb, (int)(NEd/4));
    k_ideg<<<GS, BS, 0, stream>>>(row, ideg, E);
    k_scan1<<<NB, 256, 0, stream>>>(ideg, rowptr, bsum, NE);
    k_scan2<<<1, 256, 0, stream>>>(bsum, NB);
    k_scan3<<<NB, 256, 0, stream>>>(rowptr, bsum, ideg, nstart, nend, NE, E);
    k_scatter<<<GS, BS, 0, stream>>>(row, col, ety, rowptr, cnt, jk, E);

    k_relprep<<<NR + 3*(NR+1), D, 0, stream>>>(rel_comp, rel_info, rl11, rl12,
                                               rl11a, rl12a, cloop, cw1, cw2,
                                               outp + 2*NEd, rel2all, NR);

    // e1 = leaky([l2n(ent_comp), ent_info] @ al11) @ al12
    {
        Srcs S{ ent_comp, ent_info, nullptr, 1, 1, 0 };
        k_mrow<2, 2, true><<<RB, 256, 0, stream>>>(S, wtAl11, hb, NE);
        Srcs S2{ hb, nullptr, nullptr, 0, 0, 0 };
        k_mrow<1, 1, false><<<RB, 256, 0, stream>>>(S2, wtAl12, e1b, NE);
    }

    auto conv_seq = [&](const u16* x, int l, u16* xab, u16* ubp, u16* acb,
                        u16* dstb, float* dstf){
        const float* rel2l = rel2all + (size_t)l*(NR+1)*D;
        float* gp = gp3 + (size_t)l*256;
        ConvP A4{ x, wtXatt + (size_t)l*DD, xab, ubp, rel2l + (size_t)NR*D, nullptr };
        k_mrow2<4><<<RB, 256, 0, stream>>>(A4, A4, RB, NE);
        FP fa{ x, rel2l, xab, wtScore + (size_t)l*DD, caatt + (size_t)l*D,
               rel2l + (size_t)NR*D, ubp };
        k_fedge<<<NB64, 256, 0, stream>>>(jk, rowptr, nstart, nend, fa, fa, NB64);
        ConvP A3{ ubp, wtGcn + (size_t)l*DD, acb, nullptr, nullptr, gp };
        k_mrow2<3><<<RB, 256, 0, stream>>>(A3, A3, RB, NE);
        k_bnapply<<<GS, BS, 0, stream>>>(acb, gp, inv_ne, (int)NEd, dstb, dstf);
    };

    if (wide){
        const float* rel2_0 = rel2all;
        const float* rel2_1 = rel2all + (size_t)(NR+1)*D;
        ConvP A4{ e1b, wtXatt,      xattb0, ub0, rel2_0 + (size_t)NR*D, nullptr };
        ConvP B4{ xcb, wtXatt + DD, xattb1, ub1, rel2_1 + (size_t)NR*D, nullptr };
        k_mrow2<4><<<2*RB, 256, 0, stream>>>(A4, B4, RB, NE);
        FP fa{ e1b, rel2_0, xattb0, wtScore,      caatt,     rel2_0 + (size_t)NR*D, ub0 };
        FP fb{ xcb, rel2_1, xattb1, wtScore + DD, caatt + D, rel2_1 + (size_t)NR*D, ub1 };
        k_fedge<<<2*NB64, 256, 0, stream>>>(jk, rowptr, nstart, nend, fa, fb, NB64);
        ConvP A3{ ub0, wtGcn,      accB0, nullptr, nullptr, gp3 };
        ConvP B3{ ub1, wtGcn + DD, accB1, nullptr, nullptr, gp3 + 256 };
        k_mrow2<3><<<2*RB, 256, 0, stream>>>(A3, B3, RB, NE);
        k_bnapply2<<<2*GS, BS, 0, stream>>>(accB0, gp3, ao1b,
                                            accB1, gp3 + 256, cob, outp + NEd,
                                            inv_ne, (int)NEd, GS);
    } else {
        conv_seq(e1b, 0, xattb0, ub0, accB0, ao1b, nullptr);
        conv_seq(xcb, 1, xattb0, ub0, accB0, cob, outp + NEd);
    }

    // e2 = leaky([l2n(co1), ao1] @ al21) @ al22
    {
        Srcs S{ cob, ao1b, nullptr, 0, 0, 0 };
        k_mrow<2, 2, true><<<RB, 256, 0, stream>>>(S, wtAl21, hb, NE);
        Srcs S2{ hb, nullptr, nullptr, 0, 0, 0 };
        k_mrow<1, 1, false><<<RB, 256, 0, stream>>>(S2, wtAl22, e2b, NE);
    }

    conv_seq(e2b, 2, xattb0, ub0, accB0, cob, nullptr);     // ao2 -> cob

    // out = [e1, ao1, ao2] @ allw -> d_out[0]
    {
        Srcs S{ e1b, ao1b, cob, 0, 0, 0 };
        k_mrow<3, 0, false><<<RB, 256, 0, stream>>>(S, wtAllw, outp, NE);
    }
}

// Round 18
// 663.285 us; speedup vs baseline: 1.1538x; 1.1538x over previous
//
#include <hip/hip_runtime.h>
#include <hip/hip_bf16.h>
#include <math.h>

#define D 128
#define DD 16384
#define NEMAX 96
typedef unsigned short u16;
typedef __attribute__((ext_vector_type(8))) short short8v;
typedef __attribute__((ext_vector_type(4))) short short4v;
typedef __attribute__((ext_vector_type(4))) float f32x4;

__device__ __forceinline__ u16 f2s(float v){
    union { __hip_bfloat16 h; u16 u; } c; c.h = __float2bfloat16(v); return c.u;
}
__device__ __forceinline__ float s2f(u16 u){
    union { __hip_bfloat16 h; u16 u; } c; c.u = u; return __bfloat162float(c.h);
}
__device__ __forceinline__ float lrelu(float x){ return x > 0.f ? x : 0.2f*x; }

// ---------------- small utility kernels ----------------
__global__ void k_prepz(int* __restrict__ zz, int zw, int* __restrict__ nstart,
                        int* __restrict__ nend, int nb){
    int i = blockIdx.x*blockDim.x + threadIdx.x;
    int stride = gridDim.x*blockDim.x;
    for (int k = i; k < zw; k += stride) zz[k] = 0;
    for (int k = i; k < nb; k += stride){ nstart[k] = 0x7fffffff; nend[k] = -1; }
}
__global__ void k_f2b4(const float* __restrict__ in, u16* __restrict__ out, int n4){
    for (int i = blockIdx.x*blockDim.x + threadIdx.x; i < n4; i += gridDim.x*blockDim.x){
        float4 a = ((const float4*)in)[i];
        short4v pk;
        pk[0] = (short)f2s(a.x); pk[1] = (short)f2s(a.y);
        pk[2] = (short)f2s(a.z); pk[3] = (short)f2s(a.w);
        *(short4v*)(out + (size_t)i*4) = pk;
    }
}
__global__ void k_ideg(const int* __restrict__ row, int* __restrict__ deg, int E_){
    for (int i = blockIdx.x*blockDim.x + threadIdx.x; i < E_; i += gridDim.x*blockDim.x)
        atomicAdd(&deg[row[i]], 1);
}
__global__ void k_scan1(const int* __restrict__ ideg, int* __restrict__ rowptr,
                        int* __restrict__ bsum, int n){
    __shared__ int buf[256];
    int t = threadIdx.x, i = blockIdx.x*256 + t;
    int v = (i < n) ? ideg[i] : 0;
    buf[t] = v;
    __syncthreads();
    #pragma unroll
    for (int o = 1; o < 256; o <<= 1){
        int u = (t >= o) ? buf[t-o] : 0;
        __syncthreads();
        buf[t] += u;
        __syncthreads();
    }
    if (i < n) rowptr[i] = buf[t] - v;
    if (t == 255) bsum[blockIdx.x] = buf[255];
}
__global__ void k_scan2(int* __restrict__ bsum, int nb){
    __shared__ int buf[256];
    __shared__ int carry_s;
    int t = threadIdx.x;
    if (t == 0) carry_s = 0;
    __syncthreads();
    for (int base = 0; base < nb; base += 256){
        int v = (base + t < nb) ? bsum[base + t] : 0;
        buf[t] = v;
        __syncthreads();
        #pragma unroll
        for (int o = 1; o < 256; o <<= 1){
            int u = (t >= o) ? buf[t-o] : 0;
            __syncthreads();
            buf[t] += u;
            __syncthreads();
        }
        if (base + t < nb) bsum[base + t] = carry_s + buf[t] - v;
        int last = buf[255];
        __syncthreads();
        if (t == 0) carry_s += last;
        __syncthreads();
    }
}
__global__ void k_scan3(int* __restrict__ rowptr, const int* __restrict__ bsum,
                        const int* __restrict__ ideg, int* __restrict__ nstart,
                        int* __restrict__ nend, int n, int E_){
    int i = blockIdx.x*blockDim.x + threadIdx.x;
    if (i < n){
        int rpi = rowptr[i] + bsum[i >> 8];
        rowptr[i] = rpi;
        if (i == 0) rowptr[n] = E_;
        if (ideg[i] > 0){
            int b = rpi >> 6;
            atomicMin(&nstart[b], i);
            atomicMax(&nend[b], i);
        }
    }
}
__global__ void k_scatter(const int* __restrict__ row, const int* __restrict__ col,
                          const int* __restrict__ ety, const int* __restrict__ rowptr,
                          int* __restrict__ cnt, unsigned* __restrict__ jk, int E_){
    for (int e = blockIdx.x*blockDim.x + threadIdx.x; e < E_; e += gridDim.x*blockDim.x){
        int i = row[e];
        int pos = rowptr[i] + atomicAdd(&cnt[i], 1);
        jk[pos] = ((unsigned)col[e] & 0xFFFFu) | ((unsigned)ety[e] << 16);
    }
}
__global__ void k_bnapply(const u16* __restrict__ acc, const float* __restrict__ gp,
                          float inv_ne, int n, u16* __restrict__ dstb,
                          float* __restrict__ dstf){
    int d = threadIdx.x & 127;
    float m = gp[d] * inv_ne;
    float var = gp[128 + d] * inv_ne - m*m;
    float sc = rsqrtf(var + 1e-5f);
    for (int i = blockIdx.x*blockDim.x + threadIdx.x; i < n; i += gridDim.x*blockDim.x){
        float v = s2f(acc[i]) * 0.5f;
        float r = tanhf((v - m) * sc);
        dstb[i] = f2s(r);
        if (dstf) dstf[i] = r;
    }
}
__global__ void k_bnapply2(const u16* __restrict__ acc0, const float* __restrict__ gp0,
                           u16* __restrict__ d0b,
                           const u16* __restrict__ acc1, const float* __restrict__ gp1,
                           u16* __restrict__ d1b, float* __restrict__ d1f,
                           float inv_ne, int n, int gb){
    int pb = blockIdx.x >= gb;
    const u16* acc = pb ? acc1 : acc0;
    const float* gp = pb ? gp1 : gp0;
    u16* db = pb ? d1b : d0b;
    float* df = pb ? d1f : nullptr;
    int b = blockIdx.x - (pb ? gb : 0);
    int d = threadIdx.x & 127;
    float m = gp[d] * inv_ne;
    float var = gp[128 + d] * inv_ne - m*m;
    float sc = rsqrtf(var + 1e-5f);
    for (int i = b*blockDim.x + threadIdx.x; i < n; i += gb*blockDim.x){
        float v = s2f(acc[i]) * 0.5f;
        float r = tanhf((v - m) * sc);
        db[i] = f2s(r);
        if (df) df[i] = r;
    }
}

// ---------------- batched relation prep ----------------
__global__ void k_relprep(const float* __restrict__ rel_comp, const float* __restrict__ rel_info,
        const float* __restrict__ rl11, const float* __restrict__ rl12,
        const float* __restrict__ rl11a, const float* __restrict__ rl12a,
        const float* __restrict__ cloop, const float* __restrict__ cw1,
        const float* __restrict__ cw2, float* __restrict__ pr1out,
        float* __restrict__ rel2all, int NR){
    int b = blockIdx.x, t = threadIdx.x;
    __shared__ float v[D];
    __shared__ float h[D];
    if (b < NR){
        v[t] = rel_comp[(size_t)b*D + t];
        __syncthreads();
        float a = 0.f;
        #pragma unroll 8
        for (int k = 0; k < D; k++) a += v[k] * rl11[(size_t)k*D + t];
        h[t] = lrelu(a);
        __syncthreads();
        float o = 0.f;
        #pragma unroll 8
        for (int k = 0; k < D; k++) o += h[k] * rl12[(size_t)k*D + t];
        pr1out[(size_t)b*D + t] = o;
        return;
    }
    int bb = b - NR;
    int l = bb / (NR+1), r = bb - l*(NR+1);
    float xv;
    if (r == NR)      xv = cloop[l*D + t];
    else if (l == 1)  xv = rel_comp[(size_t)r*D + t];
    else              xv = rel_info[(size_t)r*D + t];
    v[t] = xv;
    __syncthreads();
    if (l == 2 && r < NR){
        float a = 0.f;
        #pragma unroll 8
        for (int k = 0; k < D; k++) a += v[k] * rl11a[(size_t)k*D + t];
        h[t] = lrelu(a);
        __syncthreads();
        float o = 0.f;
        #pragma unroll 8
        for (int k = 0; k < D; k++) o += h[k] * rl12a[(size_t)k*D + t];
        v[t] = o;
        __syncthreads();
    }
    const float* w1 = cw1 + (size_t)l*DD;
    const float* w2 = cw2 + (size_t)l*DD;
    float a = 0.f;
    #pragma unroll 8
    for (int k = 0; k < D; k++) a += v[k] * w1[(size_t)k*D + t];
    h[t] = lrelu(a);
    __syncthreads();
    float o = 0.f;
    #pragma unroll 8
    for (int k = 0; k < D; k++) o += h[k] * w2[(size_t)k*D + t];
    rel2all[((size_t)l*(NR+1) + r)*D + t] = o;
}

// ---------------- weight prep ----------------
struct TEnt { const float* s; u16* d; int ldd; };
struct TTab { TEnt e[18]; };
__global__ void k_wprep(TTab tab){
    TEnt en = tab.e[blockIdx.x];
    int t = threadIdx.x;
    int n = t >> 1, h = t & 1;
    #pragma unroll
    for (int g = 0; g < 8; ++g){
        int k0 = h*64 + g*8;
        short8v pk;
        #pragma unroll
        for (int q = 0; q < 8; ++q) pk[q] = (short)f2s(en.s[(size_t)(k0+q)*D + n]);
        *(short8v*)(en.d + (size_t)n*en.ldd + k0) = pk;
    }
}

// ---------------- MFMA row GEMM (MLPs + final) ----------------
struct Srcs { const void* p0; const void* p1; const void* p2; int f0, f1, f2; };

template<int NSEG, int EPI, bool RSN>
__global__ __launch_bounds__(256) void k_mrow(Srcs S, const u16* __restrict__ WT,
        void* __restrict__ out, int NE_){
    __shared__ __align__(16) short As[128*128];
    int tid = threadIdx.x;
    int row0 = blockIdx.x * 128;
    int lane = tid & 63, w = tid >> 6;
    int l15 = lane & 15, lq = lane >> 4;
    int nhalf = w & 1, mquad = w >> 1;
    f32x4 acc[4][4];
    #pragma unroll
    for (int a = 0; a < 4; a++)
        #pragma unroll
        for (int b = 0; b < 4; b++) acc[a][b] = (f32x4){0.f,0.f,0.f,0.f};

    int sr = tid >> 1, sh = tid & 1;
    int rr = row0 + sr; if (rr >= NE_) rr = NE_ - 1;

    #pragma unroll
    for (int s = 0; s < NSEG; ++s){
        const void* sp = (s == 0) ? S.p0 : (s == 1) ? S.p1 : S.p2;
        int sf = (s == 0) ? S.f0 : (s == 1) ? S.f1 : S.f2;
        if (s) __syncthreads();
        #pragma unroll
        for (int g = 0; g < 8; ++g){
            int k8 = sh*64 + g*8;
            short8v pk;
            if (sf){
                const float* fp = (const float*)sp + (size_t)rr*D + k8;
                #pragma unroll
                for (int q = 0; q < 8; ++q) pk[q] = (short)f2s(fp[q]);
            } else {
                pk = *(const short8v*)((const u16*)sp + (size_t)rr*D + k8);
            }
            *(short8v*)(As + sr*D + (((k8>>3) ^ (sr&7))<<3)) = pk;
        }
        if (RSN && s == 0){
            float ss = 0.f;
            #pragma unroll
            for (int g = 0; g < 8; ++g){
                int k8 = sh*64 + g*8;
                short8v v = *(const short8v*)(As + sr*D + (((k8>>3) ^ (sr&7))<<3));
                #pragma unroll
                for (int q = 0; q < 8; ++q){ float f = s2f((u16)v[q]); ss += f*f; }
            }
            ss += __shfl_xor(ss, 1, 64);
            float rsc = 1.f / fmaxf(sqrtf(ss), 1e-12f);
            #pragma unroll
            for (int g = 0; g < 8; ++g){
                int k8 = sh*64 + g*8;
                short* ap = As + sr*D + (((k8>>3) ^ (sr&7))<<3);
                short8v v = *(const short8v*)ap;
                short8v pk;
                #pragma unroll
                for (int q = 0; q < 8; ++q) pk[q] = (short)f2s(s2f((u16)v[q]) * rsc);
                *(short8v*)ap = pk;
            }
        }
        __syncthreads();
        short8v bfr[4][4];
        #pragma unroll
        for (int nt = 0; nt < 4; ++nt)
            #pragma unroll
            for (int kk = 0; kk < 4; ++kk){
                size_t idx = (size_t)(nhalf*64 + nt*16 + l15)*(NSEG*D) + (size_t)s*D + kk*32 + lq*8;
                bfr[nt][kk] = *(const short8v*)(WT + idx);
            }
        #pragma unroll
        for (int mt = 0; mt < 4; ++mt){
            int ar = mquad*64 + mt*16 + l15;
            short8v afr[4];
            #pragma unroll
            for (int kk = 0; kk < 4; ++kk)
                afr[kk] = *(const short8v*)(As + ar*D + (((kk*4 + lq) ^ (ar&7))<<3));
            #pragma unroll
            for (int nt = 0; nt < 4; ++nt)
                #pragma unroll
                for (int kk = 0; kk < 4; ++kk)
                    acc[mt][nt] = __builtin_amdgcn_mfma_f32_16x16x32_bf16(
                        afr[kk], bfr[nt][kk], acc[mt][nt], 0, 0, 0);
        }
    }
    #pragma unroll
    for (int mt = 0; mt < 4; ++mt){
        #pragma unroll
        for (int nt = 0; nt < 4; ++nt){
            #pragma unroll
            for (int r = 0; r < 4; ++r){
                int gr = row0 + mquad*64 + mt*16 + lq*4 + r;
                if (gr >= NE_) continue;
                int c = nhalf*64 + nt*16 + l15;
                float v = acc[mt][nt][r];
                if (EPI == 0) ((float*)out)[(size_t)gr*D + c] = v;
                else ((u16*)out)[(size_t)gr*D + c] = f2s(EPI == 2 ? lrelu(v) : v);
            }
        }
    }
}

// ---------------- conv GEMM, two-problem capable ----------------
struct ConvP { const u16* x; const u16* WT; u16* out; u16* ub; const float* loop; float* gp; };

template<int MODE>
__global__ __launch_bounds__(256) void k_mrow2(ConvP A, ConvP B, int rb, int NE_){
    __shared__ __align__(16) short As[128*128];
    int pb = blockIdx.x >= rb;
    ConvP P = pb ? B : A;
    int row0 = (blockIdx.x - (pb ? rb : 0)) * 128;
    int tid = threadIdx.x;
    int lane = tid & 63, w = tid >> 6;
    int l15 = lane & 15, lq = lane >> 4;
    int nhalf = w & 1, mquad = w >> 1;
    f32x4 acc[4][4];
    #pragma unroll
    for (int a = 0; a < 4; a++)
        #pragma unroll
        for (int b = 0; b < 4; b++) acc[a][b] = (f32x4){0.f,0.f,0.f,0.f};

    int sr = tid >> 1, sh = tid & 1;
    int rr = row0 + sr; if (rr >= NE_) rr = NE_ - 1;
    #pragma unroll
    for (int g = 0; g < 8; ++g){
        int k8 = sh*64 + g*8;
        short8v pk = *(const short8v*)(P.x + (size_t)rr*D + k8);
        *(short8v*)(As + sr*D + (((k8>>3) ^ (sr&7))<<3)) = pk;
    }
    __syncthreads();
    short8v bfr[4][4];
    #pragma unroll
    for (int nt = 0; nt < 4; ++nt)
        #pragma unroll
        for (int kk = 0; kk < 4; ++kk)
            bfr[nt][kk] = *(const short8v*)(P.WT + (size_t)(nhalf*64 + nt*16 + l15)*D + kk*32 + lq*8);
    #pragma unroll
    for (int mt = 0; mt < 4; ++mt){
        int ar = mquad*64 + mt*16 + l15;
        short8v afr[4];
        #pragma unroll
        for (int kk = 0; kk < 4; ++kk)
            afr[kk] = *(const short8v*)(As + ar*D + (((kk*4 + lq) ^ (ar&7))<<3));
        #pragma unroll
        for (int nt = 0; nt < 4; ++nt)
            #pragma unroll
            for (int kk = 0; kk < 4; ++kk)
                acc[mt][nt] = __builtin_amdgcn_mfma_f32_16x16x32_bf16(
                    afr[kk], bfr[nt][kk], acc[mt][nt], 0, 0, 0);
    }
    if (MODE == 3){
        float cs[4] = {0,0,0,0}, cs2[4] = {0,0,0,0};
        #pragma unroll
        for (int mt = 0; mt < 4; ++mt)
            #pragma unroll
            for (int nt = 0; nt < 4; ++nt)
                #pragma unroll
                for (int r = 0; r < 4; ++r){
                    int gr = row0 + mquad*64 + mt*16 + lq*4 + r;
                    if (gr >= NE_) continue;
                    int c = nhalf*64 + nt*16 + l15;
                    float v = acc[mt][nt][r];
                    P.out[(size_t)gr*D + c] = f2s(v);
                    float h = v * 0.5f;
                    cs[nt] += h; cs2[nt] += h*h;
                }
        __syncthreads();
        float* ps  = (float*)As;
        float* ps2 = ps + 1024;
        int slot = mquad*4 + lq;
        #pragma unroll
        for (int nt = 0; nt < 4; ++nt){
            int c = nhalf*64 + nt*16 + l15;
            ps[slot*128 + c]  = cs[nt];
            ps2[slot*128 + c] = cs2[nt];
        }
        __syncthreads();
        if (tid < 128){
            float s = 0.f, s2 = 0.f;
            #pragma unroll
            for (int q = 0; q < 8; ++q){ s += ps[q*128 + tid]; s2 += ps2[q*128 + tid]; }
            atomicAdd(&P.gp[tid], s);
            atomicAdd(&P.gp[128 + tid], s2);
        }
    } else {
        #pragma unroll
        for (int mt = 0; mt < 4; ++mt)
            #pragma unroll
            for (int nt = 0; nt < 4; ++nt)
                #pragma unroll
                for (int r = 0; r < 4; ++r){
                    int gr = row0 + mquad*64 + mt*16 + lq*4 + r;
                    if (gr >= NE_) continue;
                    int c = nhalf*64 + nt*16 + l15;
                    P.out[(size_t)gr*D + c] = f2s(acc[mt][nt][r]);
                }
        for (int idx = tid; idx < 128*128; idx += 256){
            int r2 = idx >> 7, c = idx & 127;
            int gr = row0 + r2;
            if (gr < NE_){
                float v = s2f((u16)As[r2*D + ((((c>>3) ^ (r2&7))<<3) | (c&7))]) * P.loop[c];
                P.ub[(size_t)gr*D + c] = f2s(v);
            }
        }
    }
}

// ---------------- fused edge kernel, two-problem capable ----------------
struct FP { const u16* x; const float* rel2; const u16* xattb; const u16* WT;
            const float* aatt; const float* loop; u16* u; };

__global__ __launch_bounds__(256) void k_fedge(
        const unsigned* __restrict__ jk,
        const int* __restrict__ rowptr,
        const int* __restrict__ nstart, const int* __restrict__ nend,
        FP fa, FP fb, int nb){
    __shared__ __align__(16) short As[NEMAX*D];
    __shared__ u16 jL[NEMAX], kL[NEMAX], iL[NEMAX];
    __shared__ float sc[NEMAX];
    __shared__ float red[2][NEMAX];
    int pb = blockIdx.x >= nb;
    FP P = pb ? fb : fa;
    int b = blockIdx.x - (pb ? nb : 0);
    int ns = nstart[b];
    if (ns == 0x7fffffff) return;
    int nn = nend[b] - ns + 1;
    int tid = threadIdx.x;
    int estart = rowptr[ns];
    int ne = rowptr[ns + nn] - estart;
    if (ne > NEMAX) ne = NEMAX;
    int T = (ne + 15) >> 4;
    int nrows = T << 4;
    if (tid < ne){
        unsigned v = jk[estart + tid];
        jL[tid] = (u16)(v & 0xFFFFu); kL[tid] = (u16)(v >> 16);
    }
    if (tid < nn){
        int i = ns + tid;
        int s0 = rowptr[i] - estart, s1 = rowptr[i+1] - estart;
        if (s0 < 0) s0 = 0;
        if (s1 > NEMAX) s1 = NEMAX;
        for (int p = s0; p < s1; ++p) iL[p] = (u16)i;
    }
    __syncthreads();
    for (int it = tid; it < nrows*4; it += 256){
        int p = it >> 2, part = it & 3;
        int ps = (p < ne) ? p : (ne - 1);
        int j = jL[ps], krel = kL[ps];
        #pragma unroll
        for (int g = 0; g < 4; ++g){
            int k8 = part*32 + g*8;
            short8v sv = *(const short8v*)(P.x + (size_t)j*D + k8);
            const float* rp = P.rel2 + (size_t)krel*D + k8;
            short8v pk;
            #pragma unroll
            for (int q = 0; q < 8; ++q) pk[q] = (short)f2s(s2f((u16)sv[q]) * rp[q]);
            *(short8v*)(As + p*D + (((k8>>3) ^ (p&7))<<3)) = pk;
        }
    }
    __syncthreads();
    int lane = tid & 63, w = tid >> 6;
    int l15 = lane & 15, lq = lane >> 4;
    int nhalf = w & 1, mq = w >> 1;
    short8v bfr[4][4];
    #pragma unroll
    for (int nt = 0; nt < 4; ++nt)
        #pragma unroll
        for (int kk = 0; kk < 4; ++kk)
            bfr[nt][kk] = *(const short8v*)(P.WT + (size_t)(nhalf*64 + nt*16 + l15)*D + kk*32 + lq*8);
    float av[4];
    #pragma unroll
    for (int nt = 0; nt < 4; ++nt) av[nt] = P.aatt[nhalf*64 + nt*16 + l15];

    for (int t = mq; t < T; t += 2){
        float xv[4][4];
        #pragma unroll
        for (int r = 0; r < 4; ++r){
            int el = t*16 + lq*4 + r;
            int ep = (el < ne) ? el : (ne - 1);
            int ii = iL[ep];
            #pragma unroll
            for (int nt = 0; nt < 4; ++nt)
                xv[r][nt] = s2f(P.xattb[(size_t)ii*D + nhalf*64 + nt*16 + l15]);
        }
        int ar = t*16 + l15;
        short8v afr[4];
        #pragma unroll
        for (int kk = 0; kk < 4; ++kk)
            afr[kk] = *(const short8v*)(As + ar*D + (((kk*4 + lq) ^ (ar&7))<<3));
        f32x4 acc[4];
        #pragma unroll
        for (int nt = 0; nt < 4; ++nt) acc[nt] = (f32x4){0.f,0.f,0.f,0.f};
        #pragma unroll
        for (int nt = 0; nt < 4; ++nt)
            #pragma unroll
            for (int kk = 0; kk < 4; ++kk)
                acc[nt] = __builtin_amdgcn_mfma_f32_16x16x32_bf16(
                    afr[kk], bfr[nt][kk], acc[nt], 0, 0, 0);
        #pragma unroll
        for (int r = 0; r < 4; ++r){
            int el = t*16 + lq*4 + r;
            float p = 0.f;
            if (el < ne){
                #pragma unroll
                for (int nt = 0; nt < 4; ++nt)
                    p += lrelu(acc[nt][r] + xv[r][nt]) * av[nt];
            }
            p += __shfl_xor(p, 1, 64);
            p += __shfl_xor(p, 2, 64);
            p += __shfl_xor(p, 4, 64);
            p += __shfl_xor(p, 8, 64);
            if (l15 == 0 && el < NEMAX) red[nhalf][el] = p;
        }
    }
    __syncthreads();
    if (tid < ne) sc[tid] = expf(red[0][tid] + red[1][tid]);
    __syncthreads();
    if (tid < nn){
        int i = ns + tid;
        int s0 = rowptr[i] - estart, s1 = rowptr[i+1] - estart;
        if (s1 > NEMAX) s1 = NEMAX;
        if (s1 > s0){
            float sum = 0.f;
            for (int p = s0; p < s1; ++p) sum += sc[p];
            float coef = rsqrtf((float)(s1 - s0)) / (sum + 1e-16f);
            for (int p = s0; p < s1; ++p) sc[p] *= coef;
        }
    }
    __syncthreads();
    int c = tid & 127, nh = tid >> 7;
    float loopc = P.loop[c];
    for (int n = nh; n < nn; n += 2){
        int i = ns + n;
        int s0 = rowptr[i] - estart, s1 = rowptr[i+1] - estart;
        if (s1 > NEMAX) s1 = NEMAX;
        if (s1 <= s0) continue;
        float a = s2f(P.x[(size_t)i*D + c]) * loopc;
        int p = s0;
        for (; p + 4 <= s1; p += 4){
            float v0 = s2f((u16)As[(p+0)*D + ((((c>>3) ^ ((p+0)&7))<<3) | (c&7))]);
            float v1 = s2f((u16)As[(p+1)*D + ((((c>>3) ^ ((p+1)&7))<<3) | (c&7))]);
            float v2 = s2f((u16)As[(p+2)*D + ((((c>>3) ^ ((p+2)&7))<<3) | (c&7))]);
            float v3 = s2f((u16)As[(p+3)*D + ((((c>>3) ^ ((p+3)&7))<<3) | (c&7))]);
            a += sc[p]*v0 + sc[p+1]*v1 + sc[p+2]*v2 + sc[p+3]*v3;
        }
        for (; p < s1; ++p)
            a += sc[p] * s2f((u16)As[p*D + ((((c>>3) ^ (p&7))<<3) | (c&7))]);
        P.u[(size_t)i*D + c] = f2s(a);
    }
}

extern "C" void kernel_launch(void* const* d_in, const int* in_sizes, int n_in,
                              void* d_out, int out_size, void* d_ws, size_t ws_size,
                              hipStream_t stream){
    const int* eidx = (const int*)d_in[0];
    const int* ety  = (const int*)d_in[1];
    const float* ent_info = (const float*)d_in[2];
    const float* ent_comp = (const float*)d_in[3];
    const float* rel_comp = (const float*)d_in[4];
    const float* rel_info = (const float*)d_in[5];
    const float* al11 = (const float*)d_in[6],  *al12 = (const float*)d_in[7];
    const float* al21 = (const float*)d_in[8],  *al22 = (const float*)d_in[9];
    const float* rl11 = (const float*)d_in[10], *rl12 = (const float*)d_in[11];
    const float* rl11a = (const float*)d_in[12], *rl12a = (const float*)d_in[13];
    const float* allw = (const float*)d_in[14];
    const float* cw1 = (const float*)d_in[15], *cw2 = (const float*)d_in[16];
    const float* cgcn = (const float*)d_in[17], *cloop = (const float*)d_in[18];
    const float* cwatt = (const float*)d_in[19], *caatt = (const float*)d_in[20];

    const int E  = in_sizes[1];
    const int NE = in_sizes[2] / D;
    const int NR = in_sizes[4] / D;
    const int* row = eidx;
    const int* col = eidx + E;
    const size_t NEd = (size_t)NE * D;
    float* outp = (float*)d_out;
    const int NB64 = (E + 63) / 64;

    char* wsb = (char*)d_ws;
    size_t off = 0;
    auto takeB = [&](size_t bytes) -> void* {
        void* q = wsb + off;
        off = (off + bytes + 255) & ~(size_t)255;
        return q;
    };
    u16*   slotA = (u16*) takeB(NEd * 2);
    u16*   hb    = slotA;
    u16*   accB0 = slotA;
    u16*   xattb0= (u16*) takeB(NEd * 2);
    u16*   ub0   = (u16*) takeB(NEd * 2);
    u16*   e1b   = (u16*) takeB(NEd * 2);
    u16*   ao1b  = (u16*) takeB(NEd * 2);
    u16*   e2b   = (u16*) takeB(NEd * 2);
    u16*   cob   = (u16*) takeB(NEd * 2);
    float* rel2all = (float*)takeB((size_t)3*(NR+1)*D*4);
    int*   rowptr= (int*)  takeB((size_t)(NE+1)*4);
    unsigned* jk = (unsigned*)takeB((size_t)E*4);
    int*   bsum  = (int*)  takeB(1024*4);
    int*   nstart= (int*)  takeB((size_t)NB64*4);
    int*   nend  = (int*)  takeB((size_t)NB64*4);
    int ZW = 2*NE + 768;
    int*   zz    = (int*)  takeB((size_t)ZW*4);
    int*   ideg  = zz;
    int*   cnt   = zz + NE;
    float* gp3   = (float*)(zz + 2*NE);
    u16*   wtXatt = (u16*)takeB((size_t)3*DD*2);
    u16*   wtScore= (u16*)takeB((size_t)3*DD*2);
    u16*   wtGcn  = (u16*)takeB((size_t)3*DD*2);
    u16*   wtAl11 = (u16*)takeB((size_t)2*DD*2);
    u16*   wtAl12 = (u16*)takeB((size_t)DD*2);
    u16*   wtAl21 = (u16*)takeB((size_t)2*DD*2);
    u16*   wtAl22 = (u16*)takeB((size_t)DD*2);
    u16*   wtAllw = (u16*)takeB((size_t)3*DD*2);
    u16*   xcb   = e2b;

    size_t slab = ((NEd*2 + 255) & ~(size_t)255);
    bool wide = (off + 3*slab) <= ws_size;
    u16* xattb1 = wide ? (u16*)takeB(NEd * 2) : xattb0;
    u16* ub1    = wide ? (u16*)takeB(NEd * 2) : ub0;
    u16* accB1  = wide ? (u16*)takeB(NEd * 2) : accB0;

    const int GS = 2048, BS = 256;
    const int RB = (NE + 127) / 128;
    const int NB = (NE + 255) / 256;
    const float inv_ne = 1.f / (float)NE;

    TTab tab;
    int ti = 0;
    for (int l = 0; l < 3; ++l){
        tab.e[ti++] = { cwatt + (size_t)l*2*DD,        wtXatt  + (size_t)l*DD, 128 };
        tab.e[ti++] = { cwatt + (size_t)l*2*DD + DD,   wtScore + (size_t)l*DD, 128 };
        tab.e[ti++] = { cgcn  + (size_t)l*DD,          wtGcn   + (size_t)l*DD, 128 };
    }
    tab.e[ti++] = { al11,       wtAl11,        256 };
    tab.e[ti++] = { al11 + DD,  wtAl11 + 128,  256 };
    tab.e[ti++] = { al12,       wtAl12,        128 };
    tab.e[ti++] = { al21,       wtAl21,        256 };
    tab.e[ti++] = { al21 + DD,  wtAl21 + 128,  256 };
    tab.e[ti++] = { al22,       wtAl22,        128 };
    tab.e[ti++] = { allw,            wtAllw,        384 };
    tab.e[ti++] = { allw + DD,       wtAllw + 128,  384 };
    tab.e[ti++] = { allw + 2*DD,     wtAllw + 256,  384 };
    k_wprep<<<18, 256, 0, stream>>>(tab);

    k_prepz<<<256, BS, 0, stream>>>(zz, ZW, nstart, nend, NB64);
    k_f2b4<<<GS, BS, 0, stream>>>(ent_comp, xcb, (int)(NEd/4));
    k_ideg<<<GS, BS, 0, stream>>>(row, ideg, E);
    k_scan1<<<NB, 256, 0, stream>>>(ideg, rowptr, bsum, NE);
    k_scan2<<<1, 256, 0, stream>>>(bsum, NB);
    k_scan3<<<NB, 256, 0, stream>>>(rowptr, bsum, ideg, nstart, nend, NE, E);
    k_scatter<<<GS, BS, 0, stream>>>(row, col, ety, rowptr, cnt, jk, E);

    k_relprep<<<NR + 3*(NR+1), D, 0, stream>>>(rel_comp, rel_info, rl11, rl12,
                                               rl11a, rl12a, cloop, cw1, cw2,
                                               outp + 2*NEd, rel2all, NR);

    // e1 = leaky([l2n(ent_comp), ent_info] @ al11) @ al12
    {
        Srcs S{ ent_comp, ent_info, nullptr, 1, 1, 0 };
        k_mrow<2, 2, true><<<RB, 256, 0, stream>>>(S, wtAl11, hb, NE);
        Srcs S2{ hb, nullptr, nullptr, 0, 0, 0 };
        k_mrow<1, 1, false><<<RB, 256, 0, stream>>>(S2, wtAl12, e1b, NE);
    }

    auto conv_seq = [&](const u16* x, int l, u16* xab, u16* ubp, u16* acb,
                        u16* dstb, float* dstf){
        const float* rel2l = rel2all + (size_t)l*(NR+1)*D;
        float* gp = gp3 + (size_t)l*256;
        ConvP A4{ x, wtXatt + (size_t)l*DD, xab, ubp, rel2l + (size_t)NR*D, nullptr };
        k_mrow2<4><<<RB, 256, 0, stream>>>(A4, A4, RB, NE);
        FP fa{ x, rel2l, xab, wtScore + (size_t)l*DD, caatt + (size_t)l*D,
               rel2l + (size_t)NR*D, ubp };
        k_fedge<<<NB64, 256, 0, stream>>>(jk, rowptr, nstart, nend, fa, fa, NB64);
        ConvP A3{ ubp, wtGcn + (size_t)l*DD, acb, nullptr, nullptr, gp };
        k_mrow2<3><<<RB, 256, 0, stream>>>(A3, A3, RB, NE);
        k_bnapply<<<GS, BS, 0, stream>>>(acb, gp, inv_ne, (int)NEd, dstb, dstf);
    };

    if (wide){
        const float* rel2_0 = rel2all;
        const float* rel2_1 = rel2all + (size_t)(NR+1)*D;
        ConvP A4{ e1b, wtXatt,      xattb0, ub0, rel2_0 + (size_t)NR*D, nullptr };
        ConvP B4{ xcb, wtXatt + DD, xattb1, ub1, rel2_1 + (size_t)NR*D, nullptr };
        k_mrow2<4><<<2*RB, 256, 0, stream>>>(A4, B4, RB, NE);
        FP fa{ e1b, rel2_0, xattb0, wtScore,      caatt,     rel2_0 + (size_t)NR*D, ub0 };
        FP fb{ xcb, rel2_1, xattb1, wtScore + DD, caatt + D, rel2_1 + (size_t)NR*D, ub1 };
        k_fedge<<<2*NB64, 256, 0, stream>>>(jk, rowptr, nstart, nend, fa, fb, NB64);
        ConvP A3{ ub0, wtGcn,      accB0, nullptr, nullptr, gp3 };
        ConvP B3{ ub1, wtGcn + DD, accB1, nullptr, nullptr, gp3 + 256 };
        k_mrow2<3><<<2*RB, 256, 0, stream>>>(A3, B3, RB, NE);
        k_bnapply2<<<2*GS, BS, 0, stream>>>(accB0, gp3, ao1b,
                                            accB1, gp3 + 256, cob, outp + NEd,
                                            inv_ne, (int)NEd, GS);
    } else {
        conv_seq(e1b, 0, xattb0, ub0, accB0, ao1b, nullptr);
        conv_seq(xcb, 1, xattb0, ub0, accB0, cob, outp + NEd);
    }

    // e2 = leaky([l2n(co1), ao1] @ al21) @ al22
    {
        Srcs S{ cob, ao1b, nullptr, 0, 0, 0 };
        k_mrow<2, 2, true><<<RB, 256, 0, stream>>>(S, wtAl21, hb, NE);
        Srcs S2{ hb, nullptr, nullptr, 0, 0, 0 };
        k_mrow<1, 1, false><<<RB, 256, 0, stream>>>(S2, wtAl22, e2b, NE);
    }

    conv_seq(e2b, 2, xattb0, ub0, accB0, cob, nullptr);     // ao2 -> cob

    // out = [e1, ao1, ao2] @ allw -> d_out[0]
    {
        Srcs S{ e1b, ao1b, cob, 0, 0, 0 };
        k_mrow<3, 0, false><<<RB, 256, 0, stream>>>(S, wtAllw, outp, NE);
    }
}

// Round 19
// 634.131 us; speedup vs baseline: 1.2068x; 1.0460x over previous
//
#include <hip/hip_runtime.h>
#include <hip/hip_bf16.h>
#include <math.h>

#define D 128
#define DD 16384
#define NEMAX 96
typedef unsigned short u16;
typedef __attribute__((ext_vector_type(8))) short short8v;
typedef __attribute__((ext_vector_type(4))) short short4v;
typedef __attribute__((ext_vector_type(4))) float f32x4;

__device__ __forceinline__ u16 f2s(float v){
    union { __hip_bfloat16 h; u16 u; } c; c.h = __float2bfloat16(v); return c.u;
}
__device__ __forceinline__ float s2f(u16 u){
    union { __hip_bfloat16 h; u16 u; } c; c.u = u; return __bfloat162float(c.h);
}
__device__ __forceinline__ float lrelu(float x){ return x > 0.f ? x : 0.2f*x; }

// ---------------- small utility kernels ----------------
__global__ void k_prepz(int* __restrict__ zz, int zw, int* __restrict__ nstart,
                        int* __restrict__ nend, int nb){
    int i = blockIdx.x*blockDim.x + threadIdx.x;
    int stride = gridDim.x*blockDim.x;
    for (int k = i; k < zw; k += stride) zz[k] = 0;
    for (int k = i; k < nb; k += stride){ nstart[k] = 0x7fffffff; nend[k] = -1; }
}
__global__ void k_zeroi(int* __restrict__ p, int n){
    for (int i = blockIdx.x*blockDim.x + threadIdx.x; i < n; i += gridDim.x*blockDim.x)
        p[i] = 0;
}
__global__ void k_f2b4(const float* __restrict__ in, u16* __restrict__ out, int n4){
    for (int i = blockIdx.x*blockDim.x + threadIdx.x; i < n4; i += gridDim.x*blockDim.x){
        float4 a = ((const float4*)in)[i];
        short4v pk;
        pk[0] = (short)f2s(a.x); pk[1] = (short)f2s(a.y);
        pk[2] = (short)f2s(a.z); pk[3] = (short)f2s(a.w);
        *(short4v*)(out + (size_t)i*4) = pk;
    }
}
__global__ void k_ideg(const int* __restrict__ row, int* __restrict__ deg, int E_){
    for (int i = blockIdx.x*blockDim.x + threadIdx.x; i < E_; i += gridDim.x*blockDim.x)
        atomicAdd(&deg[row[i]], 1);
}
__global__ void k_scan1(const int* __restrict__ ideg, int* __restrict__ rowptr,
                        int* __restrict__ bsum, int n){
    __shared__ int buf[256];
    int t = threadIdx.x, i = blockIdx.x*256 + t;
    int v = (i < n) ? ideg[i] : 0;
    buf[t] = v;
    __syncthreads();
    #pragma unroll
    for (int o = 1; o < 256; o <<= 1){
        int u = (t >= o) ? buf[t-o] : 0;
        __syncthreads();
        buf[t] += u;
        __syncthreads();
    }
    if (i < n) rowptr[i] = buf[t] - v;
    if (t == 255) bsum[blockIdx.x] = buf[255];
}
__global__ void k_scan2(int* __restrict__ bsum, int nb){
    __shared__ int buf[256];
    __shared__ int carry_s;
    int t = threadIdx.x;
    if (t == 0) carry_s = 0;
    __syncthreads();
    for (int base = 0; base < nb; base += 256){
        int v = (base + t < nb) ? bsum[base + t] : 0;
        buf[t] = v;
        __syncthreads();
        #pragma unroll
        for (int o = 1; o < 256; o <<= 1){
            int u = (t >= o) ? buf[t-o] : 0;
            __syncthreads();
            buf[t] += u;
            __syncthreads();
        }
        if (base + t < nb) bsum[base + t] = carry_s + buf[t] - v;
        int last = buf[255];
        __syncthreads();
        if (t == 0) carry_s += last;
        __syncthreads();
    }
}
__global__ void k_scan3(int* __restrict__ rowptr, const int* __restrict__ bsum,
                        const int* __restrict__ ideg, int* __restrict__ nstart,
                        int* __restrict__ nend, int n, int E_){
    int i = blockIdx.x*blockDim.x + threadIdx.x;
    if (i < n){
        int rpi = rowptr[i] + bsum[i >> 8];
        rowptr[i] = rpi;
        if (i == 0) rowptr[n] = E_;
        if (ideg[i] > 0){
            int b = rpi >> 6;
            atomicMin(&nstart[b], i);
            atomicMax(&nend[b], i);
        }
    }
}
__global__ void k_scatter(const int* __restrict__ row, const int* __restrict__ col,
                          const int* __restrict__ ety, const int* __restrict__ rowptr,
                          int* __restrict__ cnt, unsigned* __restrict__ jk, int E_){
    for (int e = blockIdx.x*blockDim.x + threadIdx.x; e < E_; e += gridDim.x*blockDim.x){
        int i = row[e];
        int pos = rowptr[i] + atomicAdd(&cnt[i], 1);
        jk[pos] = ((unsigned)col[e] & 0xFFFFu) | ((unsigned)ety[e] << 16);
    }
}
__global__ void k_bnapply(const u16* __restrict__ acc, const float* __restrict__ gp,
                          float inv_ne, int n, u16* __restrict__ dstb,
                          float* __restrict__ dstf){
    int d = threadIdx.x & 127;
    float m = gp[d] * inv_ne;
    float var = gp[128 + d] * inv_ne - m*m;
    float sc = rsqrtf(var + 1e-5f);
    for (int i = blockIdx.x*blockDim.x + threadIdx.x; i < n; i += gridDim.x*blockDim.x){
        float v = s2f(acc[i]) * 0.5f;
        float r = tanhf((v - m) * sc);
        dstb[i] = f2s(r);
        if (dstf) dstf[i] = r;
    }
}
__global__ void k_bnapply2(const u16* __restrict__ acc0, const float* __restrict__ gp0,
                           u16* __restrict__ d0b,
                           const u16* __restrict__ acc1, const float* __restrict__ gp1,
                           u16* __restrict__ d1b, float* __restrict__ d1f,
                           float inv_ne, int n, int gb){
    int pb = blockIdx.x >= gb;
    const u16* acc = pb ? acc1 : acc0;
    const float* gp = pb ? gp1 : gp0;
    u16* db = pb ? d1b : d0b;
    float* df = pb ? d1f : nullptr;
    int b = blockIdx.x - (pb ? gb : 0);
    int d = threadIdx.x & 127;
    float m = gp[d] * inv_ne;
    float var = gp[128 + d] * inv_ne - m*m;
    float sc = rsqrtf(var + 1e-5f);
    for (int i = b*blockDim.x + threadIdx.x; i < n; i += gb*blockDim.x){
        float v = s2f(acc[i]) * 0.5f;
        float r = tanhf((v - m) * sc);
        db[i] = f2s(r);
        if (df) df[i] = r;
    }
}

// ---------------- batched relation prep ----------------
__global__ void k_relprep(const float* __restrict__ rel_comp, const float* __restrict__ rel_info,
        const float* __restrict__ rl11, const float* __restrict__ rl12,
        const float* __restrict__ rl11a, const float* __restrict__ rl12a,
        const float* __restrict__ cloop, const float* __restrict__ cw1,
        const float* __restrict__ cw2, float* __restrict__ pr1out,
        float* __restrict__ rel2all, int NR){
    int b = blockIdx.x, t = threadIdx.x;
    __shared__ float v[D];
    __shared__ float h[D];
    if (b < NR){
        v[t] = rel_comp[(size_t)b*D + t];
        __syncthreads();
        float a = 0.f;
        #pragma unroll 8
        for (int k = 0; k < D; k++) a += v[k] * rl11[(size_t)k*D + t];
        h[t] = lrelu(a);
        __syncthreads();
        float o = 0.f;
        #pragma unroll 8
        for (int k = 0; k < D; k++) o += h[k] * rl12[(size_t)k*D + t];
        pr1out[(size_t)b*D + t] = o;
        return;
    }
    int bb = b - NR;
    int l = bb / (NR+1), r = bb - l*(NR+1);
    float xv;
    if (r == NR)      xv = cloop[l*D + t];
    else if (l == 1)  xv = rel_comp[(size_t)r*D + t];
    else              xv = rel_info[(size_t)r*D + t];
    v[t] = xv;
    __syncthreads();
    if (l == 2 && r < NR){
        float a = 0.f;
        #pragma unroll 8
        for (int k = 0; k < D; k++) a += v[k] * rl11a[(size_t)k*D + t];
        h[t] = lrelu(a);
        __syncthreads();
        float o = 0.f;
        #pragma unroll 8
        for (int k = 0; k < D; k++) o += h[k] * rl12a[(size_t)k*D + t];
        v[t] = o;
        __syncthreads();
    }
    const float* w1 = cw1 + (size_t)l*DD;
    const float* w2 = cw2 + (size_t)l*DD;
    float a = 0.f;
    #pragma unroll 8
    for (int k = 0; k < D; k++) a += v[k] * w1[(size_t)k*D + t];
    h[t] = lrelu(a);
    __syncthreads();
    float o = 0.f;
    #pragma unroll 8
    for (int k = 0; k < D; k++) o += h[k] * w2[(size_t)k*D + t];
    rel2all[((size_t)l*(NR+1) + r)*D + t] = o;
}

// ---------------- weight prep ----------------
struct TEnt { const float* s; u16* d; int ldd; };
struct TTab { TEnt e[18]; };
__global__ void k_wprep(TTab tab){
    TEnt en = tab.e[blockIdx.x];
    int t = threadIdx.x;
    int n = t >> 1, h = t & 1;
    #pragma unroll
    for (int g = 0; g < 8; ++g){
        int k0 = h*64 + g*8;
        short8v pk;
        #pragma unroll
        for (int q = 0; q < 8; ++q) pk[q] = (short)f2s(en.s[(size_t)(k0+q)*D + n]);
        *(short8v*)(en.d + (size_t)n*en.ldd + k0) = pk;
    }
}
// combined gcn weight: cols 0-127 = Wgcn; 128-255 = diag(loop)*Wgcn
__global__ void k_wgl(const u16* __restrict__ wtGcn, const float* __restrict__ rel2all,
                      int NR, u16* __restrict__ wtGcnC){
    int l = blockIdx.x, t = threadIdx.x;
    const u16* src = wtGcn + (size_t)l*DD;
    const float* loop = rel2all + ((size_t)l*(NR+1) + NR)*D;
    u16* dst = wtGcnC + (size_t)l*2*DD;
    for (int idx = t; idx < DD; idx += 256){
        int n = idx >> 7, k = idx & 127;
        u16 w = src[idx];
        dst[(size_t)n*256 + k] = w;
        dst[(size_t)n*256 + 128 + k] = f2s(s2f(w) * loop[k]);
    }
}

// ---------------- MFMA row GEMM (MLPs + final) ----------------
struct Srcs { const void* p0; const void* p1; const void* p2; int f0, f1, f2; };

template<int NSEG, int EPI, bool RSN>
__global__ __launch_bounds__(256) void k_mrow(Srcs S, const u16* __restrict__ WT,
        void* __restrict__ out, int NE_){
    __shared__ __align__(16) short As[128*128];
    int tid = threadIdx.x;
    int row0 = blockIdx.x * 128;
    int lane = tid & 63, w = tid >> 6;
    int l15 = lane & 15, lq = lane >> 4;
    int nhalf = w & 1, mquad = w >> 1;
    f32x4 acc[4][4];
    #pragma unroll
    for (int a = 0; a < 4; a++)
        #pragma unroll
        for (int b = 0; b < 4; b++) acc[a][b] = (f32x4){0.f,0.f,0.f,0.f};

    int sr = tid >> 1, sh = tid & 1;
    int rr = row0 + sr; if (rr >= NE_) rr = NE_ - 1;

    #pragma unroll
    for (int s = 0; s < NSEG; ++s){
        const void* sp = (s == 0) ? S.p0 : (s == 1) ? S.p1 : S.p2;
        int sf = (s == 0) ? S.f0 : (s == 1) ? S.f1 : S.f2;
        if (s) __syncthreads();
        #pragma unroll
        for (int g = 0; g < 8; ++g){
            int k8 = sh*64 + g*8;
            short8v pk;
            if (sf){
                const float* fp = (const float*)sp + (size_t)rr*D + k8;
                #pragma unroll
                for (int q = 0; q < 8; ++q) pk[q] = (short)f2s(fp[q]);
            } else {
                pk = *(const short8v*)((const u16*)sp + (size_t)rr*D + k8);
            }
            *(short8v*)(As + sr*D + (((k8>>3) ^ (sr&7))<<3)) = pk;
        }
        if (RSN && s == 0){
            float ss = 0.f;
            #pragma unroll
            for (int g = 0; g < 8; ++g){
                int k8 = sh*64 + g*8;
                short8v v = *(const short8v*)(As + sr*D + (((k8>>3) ^ (sr&7))<<3));
                #pragma unroll
                for (int q = 0; q < 8; ++q){ float f = s2f((u16)v[q]); ss += f*f; }
            }
            ss += __shfl_xor(ss, 1, 64);
            float rsc = 1.f / fmaxf(sqrtf(ss), 1e-12f);
            #pragma unroll
            for (int g = 0; g < 8; ++g){
                int k8 = sh*64 + g*8;
                short* ap = As + sr*D + (((k8>>3) ^ (sr&7))<<3);
                short8v v = *(const short8v*)ap;
                short8v pk;
                #pragma unroll
                for (int q = 0; q < 8; ++q) pk[q] = (short)f2s(s2f((u16)v[q]) * rsc);
                *(short8v*)ap = pk;
            }
        }
        __syncthreads();
        short8v bfr[4][4];
        #pragma unroll
        for (int nt = 0; nt < 4; ++nt)
            #pragma unroll
            for (int kk = 0; kk < 4; ++kk){
                size_t idx = (size_t)(nhalf*64 + nt*16 + l15)*(NSEG*D) + (size_t)s*D + kk*32 + lq*8;
                bfr[nt][kk] = *(const short8v*)(WT + idx);
            }
        #pragma unroll
        for (int mt = 0; mt < 4; ++mt){
            int ar = mquad*64 + mt*16 + l15;
            short8v afr[4];
            #pragma unroll
            for (int kk = 0; kk < 4; ++kk)
                afr[kk] = *(const short8v*)(As + ar*D + (((kk*4 + lq) ^ (ar&7))<<3));
            #pragma unroll
            for (int nt = 0; nt < 4; ++nt)
                #pragma unroll
                for (int kk = 0; kk < 4; ++kk)
                    acc[mt][nt] = __builtin_amdgcn_mfma_f32_16x16x32_bf16(
                        afr[kk], bfr[nt][kk], acc[mt][nt], 0, 0, 0);
        }
    }
    #pragma unroll
    for (int mt = 0; mt < 4; ++mt){
        #pragma unroll
        for (int nt = 0; nt < 4; ++nt){
            #pragma unroll
            for (int r = 0; r < 4; ++r){
                int gr = row0 + mquad*64 + mt*16 + lq*4 + r;
                if (gr >= NE_) continue;
                int c = nhalf*64 + nt*16 + l15;
                float v = acc[mt][nt][r];
                if (EPI == 0) ((float*)out)[(size_t)gr*D + c] = v;
                else ((u16*)out)[(size_t)gr*D + c] = f2s(EPI == 2 ? lrelu(v) : v);
            }
        }
    }
}

// ---------------- xatt GEMM, two-problem ----------------
struct XP { const u16* x; const u16* WT; u16* out; };

__global__ __launch_bounds__(256) void k_xatt2(XP A, XP B, int rb, int NE_){
    __shared__ __align__(16) short As[128*128];
    int pb = blockIdx.x >= rb;
    XP P = pb ? B : A;
    int row0 = (blockIdx.x - (pb ? rb : 0)) * 128;
    int tid = threadIdx.x;
    int lane = tid & 63, w = tid >> 6;
    int l15 = lane & 15, lq = lane >> 4;
    int nhalf = w & 1, mquad = w >> 1;
    f32x4 acc[4][4];
    #pragma unroll
    for (int a = 0; a < 4; a++)
        #pragma unroll
        for (int b = 0; b < 4; b++) acc[a][b] = (f32x4){0.f,0.f,0.f,0.f};
    int sr = tid >> 1, sh = tid & 1;
    int rr = row0 + sr; if (rr >= NE_) rr = NE_ - 1;
    #pragma unroll
    for (int g = 0; g < 8; ++g){
        int k8 = sh*64 + g*8;
        short8v pk = *(const short8v*)(P.x + (size_t)rr*D + k8);
        *(short8v*)(As + sr*D + (((k8>>3) ^ (sr&7))<<3)) = pk;
    }
    __syncthreads();
    short8v bfr[4][4];
    #pragma unroll
    for (int nt = 0; nt < 4; ++nt)
        #pragma unroll
        for (int kk = 0; kk < 4; ++kk)
            bfr[nt][kk] = *(const short8v*)(P.WT + (size_t)(nhalf*64 + nt*16 + l15)*D + kk*32 + lq*8);
    #pragma unroll
    for (int mt = 0; mt < 4; ++mt){
        int ar = mquad*64 + mt*16 + l15;
        short8v afr[4];
        #pragma unroll
        for (int kk = 0; kk < 4; ++kk)
            afr[kk] = *(const short8v*)(As + ar*D + (((kk*4 + lq) ^ (ar&7))<<3));
        #pragma unroll
        for (int nt = 0; nt < 4; ++nt)
            #pragma unroll
            for (int kk = 0; kk < 4; ++kk)
                acc[mt][nt] = __builtin_amdgcn_mfma_f32_16x16x32_bf16(
                    afr[kk], bfr[nt][kk], acc[mt][nt], 0, 0, 0);
    }
    #pragma unroll
    for (int mt = 0; mt < 4; ++mt)
        #pragma unroll
        for (int nt = 0; nt < 4; ++nt)
            #pragma unroll
            for (int r = 0; r < 4; ++r){
                int gr = row0 + mquad*64 + mt*16 + lq*4 + r;
                if (gr >= NE_) continue;
                int c = nhalf*64 + nt*16 + l15;
                P.out[(size_t)gr*D + c] = f2s(acc[mt][nt][r]);
            }
}

// ---------------- gcn GEMM (K=256: msg@W + x@loopW), two-problem, BN stats ----------------
struct GP { const u16* ub; const u16* x; const u16* WT; u16* out; float* gp; };

__global__ __launch_bounds__(256) void k_gcn2(GP A, GP B, int rb, int NE_){
    __shared__ __align__(16) short As[128*128];
    int pb = blockIdx.x >= rb;
    GP P = pb ? B : A;
    int row0 = (blockIdx.x - (pb ? rb : 0)) * 128;
    int tid = threadIdx.x;
    int lane = tid & 63, w = tid >> 6;
    int l15 = lane & 15, lq = lane >> 4;
    int nhalf = w & 1, mquad = w >> 1;
    f32x4 acc[4][4];
    #pragma unroll
    for (int a = 0; a < 4; a++)
        #pragma unroll
        for (int b = 0; b < 4; b++) acc[a][b] = (f32x4){0.f,0.f,0.f,0.f};
    int sr = tid >> 1, sh = tid & 1;
    int rr = row0 + sr; if (rr >= NE_) rr = NE_ - 1;
    #pragma unroll
    for (int s = 0; s < 2; ++s){
        const u16* sp = s ? P.x : P.ub;
        if (s) __syncthreads();
        #pragma unroll
        for (int g = 0; g < 8; ++g){
            int k8 = sh*64 + g*8;
            short8v pk = *(const short8v*)(sp + (size_t)rr*D + k8);
            *(short8v*)(As + sr*D + (((k8>>3) ^ (sr&7))<<3)) = pk;
        }
        __syncthreads();
        short8v bfr[4][4];
        #pragma unroll
        for (int nt = 0; nt < 4; ++nt)
            #pragma unroll
            for (int kk = 0; kk < 4; ++kk){
                size_t idx = (size_t)(nhalf*64 + nt*16 + l15)*256 + (size_t)s*D + kk*32 + lq*8;
                bfr[nt][kk] = *(const short8v*)(P.WT + idx);
            }
        #pragma unroll
        for (int mt = 0; mt < 4; ++mt){
            int ar = mquad*64 + mt*16 + l15;
            short8v afr[4];
            #pragma unroll
            for (int kk = 0; kk < 4; ++kk)
                afr[kk] = *(const short8v*)(As + ar*D + (((kk*4 + lq) ^ (ar&7))<<3));
            #pragma unroll
            for (int nt = 0; nt < 4; ++nt)
                #pragma unroll
                for (int kk = 0; kk < 4; ++kk)
                    acc[mt][nt] = __builtin_amdgcn_mfma_f32_16x16x32_bf16(
                        afr[kk], bfr[nt][kk], acc[mt][nt], 0, 0, 0);
        }
    }
    float cs[4] = {0,0,0,0}, cs2[4] = {0,0,0,0};
    #pragma unroll
    for (int mt = 0; mt < 4; ++mt)
        #pragma unroll
        for (int nt = 0; nt < 4; ++nt)
            #pragma unroll
            for (int r = 0; r < 4; ++r){
                int gr = row0 + mquad*64 + mt*16 + lq*4 + r;
                if (gr >= NE_) continue;
                int c = nhalf*64 + nt*16 + l15;
                float v = acc[mt][nt][r];
                P.out[(size_t)gr*D + c] = f2s(v);
                float h = v * 0.5f;
                cs[nt] += h; cs2[nt] += h*h;
            }
    __syncthreads();
    float* ps  = (float*)As;
    float* ps2 = ps + 1024;
    int slot = mquad*4 + lq;
    #pragma unroll
    for (int nt = 0; nt < 4; ++nt){
        int c = nhalf*64 + nt*16 + l15;
        ps[slot*128 + c]  = cs[nt];
        ps2[slot*128 + c] = cs2[nt];
    }
    __syncthreads();
    if (tid < 128){
        float s = 0.f, s2 = 0.f;
        #pragma unroll
        for (int q = 0; q < 8; ++q){ s += ps[q*128 + tid]; s2 += ps2[q*128 + tid]; }
        atomicAdd(&P.gp[tid], s);
        atomicAdd(&P.gp[128 + tid], s2);
    }
}

// ---------------- fused edge kernel, two-problem: writes msg only ----------------
struct FP { const u16* x; const float* rel2; const u16* xattb; const u16* WT;
            const float* aatt; u16* u; };

__global__ __launch_bounds__(256) void k_fedge(
        const unsigned* __restrict__ jk,
        const int* __restrict__ rowptr,
        const int* __restrict__ nstart, const int* __restrict__ nend,
        FP fa, FP fb, int nb){
    __shared__ __align__(16) short As[NEMAX*D];
    __shared__ u16 jL[NEMAX], kL[NEMAX], iL[NEMAX];
    __shared__ float sc[NEMAX];
    __shared__ float red[2][NEMAX];
    int pb = blockIdx.x >= nb;
    FP P = pb ? fb : fa;
    int b = blockIdx.x - (pb ? nb : 0);
    int ns = nstart[b];
    if (ns == 0x7fffffff) return;
    int nn = nend[b] - ns + 1;
    int tid = threadIdx.x;
    int estart = rowptr[ns];
    int ne = rowptr[ns + nn] - estart;
    if (ne > NEMAX) ne = NEMAX;
    int T = (ne + 15) >> 4;
    int nrows = T << 4;
    if (tid < ne){
        unsigned v = jk[estart + tid];
        jL[tid] = (u16)(v & 0xFFFFu); kL[tid] = (u16)(v >> 16);
    }
    if (tid < nn){
        int i = ns + tid;
        int s0 = rowptr[i] - estart, s1 = rowptr[i+1] - estart;
        if (s0 < 0) s0 = 0;
        if (s1 > NEMAX) s1 = NEMAX;
        for (int p = s0; p < s1; ++p) iL[p] = (u16)i;
    }
    __syncthreads();
    for (int it = tid; it < nrows*4; it += 256){
        int p = it >> 2, part = it & 3;
        int ps = (p < ne) ? p : (ne - 1);
        int j = jL[ps], krel = kL[ps];
        #pragma unroll
        for (int g = 0; g < 4; ++g){
            int k8 = part*32 + g*8;
            short8v sv = *(const short8v*)(P.x + (size_t)j*D + k8);
            const float* rp = P.rel2 + (size_t)krel*D + k8;
            short8v pk;
            #pragma unroll
            for (int q = 0; q < 8; ++q) pk[q] = (short)f2s(s2f((u16)sv[q]) * rp[q]);
            *(short8v*)(As + p*D + (((k8>>3) ^ (p&7))<<3)) = pk;
        }
    }
    __syncthreads();
    int lane = tid & 63, w = tid >> 6;
    int l15 = lane & 15, lq = lane >> 4;
    int nhalf = w & 1, mq = w >> 1;
    short8v bfr[4][4];
    #pragma unroll
    for (int nt = 0; nt < 4; ++nt)
        #pragma unroll
        for (int kk = 0; kk < 4; ++kk)
            bfr[nt][kk] = *(const short8v*)(P.WT + (size_t)(nhalf*64 + nt*16 + l15)*D + kk*32 + lq*8);
    float av[4];
    #pragma unroll
    for (int nt = 0; nt < 4; ++nt) av[nt] = P.aatt[nhalf*64 + nt*16 + l15];

    for (int t = mq; t < T; t += 2){
        float xv[4][4];
        #pragma unroll
        for (int r = 0; r < 4; ++r){
            int el = t*16 + lq*4 + r;
            int ep = (el < ne) ? el : (ne - 1);
            int ii = iL[ep];
            #pragma unroll
            for (int nt = 0; nt < 4; ++nt)
                xv[r][nt] = s2f(P.xattb[(size_t)ii*D + nhalf*64 + nt*16 + l15]);
        }
        int ar = t*16 + l15;
        short8v afr[4];
        #pragma unroll
        for (int kk = 0; kk < 4; ++kk)
            afr[kk] = *(const short8v*)(As + ar*D + (((kk*4 + lq) ^ (ar&7))<<3));
        f32x4 acc[4];
        #pragma unroll
        for (int nt = 0; nt < 4; ++nt) acc[nt] = (f32x4){0.f,0.f,0.f,0.f};
        #pragma unroll
        for (int nt = 0; nt < 4; ++nt)
            #pragma unroll
            for (int kk = 0; kk < 4; ++kk)
                acc[nt] = __builtin_amdgcn_mfma_f32_16x16x32_bf16(
                    afr[kk], bfr[nt][kk], acc[nt], 0, 0, 0);
        #pragma unroll
        for (int r = 0; r < 4; ++r){
            int el = t*16 + lq*4 + r;
            float p = 0.f;
            if (el < ne){
                #pragma unroll
                for (int nt = 0; nt < 4; ++nt)
                    p += lrelu(acc[nt][r] + xv[r][nt]) * av[nt];
            }
            p += __shfl_xor(p, 1, 64);
            p += __shfl_xor(p, 2, 64);
            p += __shfl_xor(p, 4, 64);
            p += __shfl_xor(p, 8, 64);
            if (l15 == 0 && el < NEMAX) red[nhalf][el] = p;
        }
    }
    __syncthreads();
    if (tid < ne) sc[tid] = expf(red[0][tid] + red[1][tid]);
    __syncthreads();
    if (tid < nn){
        int i = ns + tid;
        int s0 = rowptr[i] - estart, s1 = rowptr[i+1] - estart;
        if (s1 > NEMAX) s1 = NEMAX;
        if (s1 > s0){
            float sum = 0.f;
            for (int p = s0; p < s1; ++p) sum += sc[p];
            float coef = rsqrtf((float)(s1 - s0)) / (sum + 1e-16f);
            for (int p = s0; p < s1; ++p) sc[p] *= coef;
        }
    }
    __syncthreads();
    // msg only (self-loop folded into gcn GEMM); deg-0 rows stay zero from init
    int c = tid & 127, nh = tid >> 7;
    for (int n = nh; n < nn; n += 2){
        int i = ns + n;
        int s0 = rowptr[i] - estart, s1 = rowptr[i+1] - estart;
        if (s1 > NEMAX) s1 = NEMAX;
        if (s1 <= s0) continue;
        float a = 0.f;
        int p = s0;
        for (; p + 4 <= s1; p += 4){
            float v0 = s2f((u16)As[(p+0)*D + ((((c>>3) ^ ((p+0)&7))<<3) | (c&7))]);
            float v1 = s2f((u16)As[(p+1)*D + ((((c>>3) ^ ((p+1)&7))<<3) | (c&7))]);
            float v2 = s2f((u16)As[(p+2)*D + ((((c>>3) ^ ((p+2)&7))<<3) | (c&7))]);
            float v3 = s2f((u16)As[(p+3)*D + ((((c>>3) ^ ((p+3)&7))<<3) | (c&7))]);
            a += sc[p]*v0 + sc[p+1]*v1 + sc[p+2]*v2 + sc[p+3]*v3;
        }
        for (; p < s1; ++p)
            a += sc[p] * s2f((u16)As[p*D + ((((c>>3) ^ (p&7))<<3) | (c&7))]);
        P.u[(size_t)i*D + c] = f2s(a);
    }
}

extern "C" void kernel_launch(void* const* d_in, const int* in_sizes, int n_in,
                              void* d_out, int out_size, void* d_ws, size_t ws_size,
                              hipStream_t stream){
    const int* eidx = (const int*)d_in[0];
    const int* ety  = (const int*)d_in[1];
    const float* ent_info = (const float*)d_in[2];
    const float* ent_comp = (const float*)d_in[3];
    const float* rel_comp = (const float*)d_in[4];
    const float* rel_info = (const float*)d_in[5];
    const float* al11 = (const float*)d_in[6],  *al12 = (const float*)d_in[7];
    const float* al21 = (const float*)d_in[8],  *al22 = (const float*)d_in[9];
    const float* rl11 = (const float*)d_in[10], *rl12 = (const float*)d_in[11];
    const float* rl11a = (const float*)d_in[12], *rl12a = (const float*)d_in[13];
    const float* allw = (const float*)d_in[14];
    const float* cw1 = (const float*)d_in[15], *cw2 = (const float*)d_in[16];
    const float* cgcn = (const float*)d_in[17], *cloop = (const float*)d_in[18];
    const float* cwatt = (const float*)d_in[19], *caatt = (const float*)d_in[20];

    const int E  = in_sizes[1];
    const int NE = in_sizes[2] / D;
    const int NR = in_sizes[4] / D;
    const int* row = eidx;
    const int* col = eidx + E;
    const size_t NEd = (size_t)NE * D;
    float* outp = (float*)d_out;
    const int NB64 = (E + 63) / 64;

    char* wsb = (char*)d_ws;
    size_t off = 0;
    auto takeB = [&](size_t bytes) -> void* {
        void* q = wsb + off;
        off = (off + bytes + 255) & ~(size_t)255;
        return q;
    };
    u16*   slotA = (u16*) takeB(NEd * 2);
    u16*   hb    = slotA;
    u16*   accB0 = slotA;
    u16*   xattb0= (u16*) takeB(NEd * 2);
    u16*   ub0   = (u16*) takeB(NEd * 2);
    u16*   e1b   = (u16*) takeB(NEd * 2);
    u16*   ao1b  = (u16*) takeB(NEd * 2);
    u16*   e2b   = (u16*) takeB(NEd * 2);
    u16*   cob   = (u16*) takeB(NEd * 2);
    float* rel2all = (float*)takeB((size_t)3*(NR+1)*D*4);
    int*   rowptr= (int*)  takeB((size_t)(NE+1)*4);
    unsigned* jk = (unsigned*)takeB((size_t)E*4);
    int*   bsum  = (int*)  takeB(1024*4);
    int*   nstart= (int*)  takeB((size_t)NB64*4);
    int*   nend  = (int*)  takeB((size_t)NB64*4);
    int ZW = 2*NE + 768;
    int*   zz    = (int*)  takeB((size_t)ZW*4);
    int*   ideg  = zz;
    int*   cnt   = zz + NE;
    float* gp3   = (float*)(zz + 2*NE);
    u16*   wtXatt = (u16*)takeB((size_t)3*DD*2);
    u16*   wtScore= (u16*)takeB((size_t)3*DD*2);
    u16*   wtGcn  = (u16*)takeB((size_t)3*DD*2);
    u16*   wtGcnC = (u16*)takeB((size_t)3*2*DD*2);
    u16*   wtAl11 = (u16*)takeB((size_t)2*DD*2);
    u16*   wtAl12 = (u16*)takeB((size_t)DD*2);
    u16*   wtAl21 = (u16*)takeB((size_t)2*DD*2);
    u16*   wtAl22 = (u16*)takeB((size_t)DD*2);
    u16*   wtAllw = (u16*)takeB((size_t)3*DD*2);
    u16*   xcb   = e2b;

    size_t slab = ((NEd*2 + 255) & ~(size_t)255);
    bool wide = (off + 3*slab) <= ws_size;
    u16* xattb1 = wide ? (u16*)takeB(NEd * 2) : xattb0;
    u16* ub1    = wide ? (u16*)takeB(NEd * 2) : ub0;
    u16* accB1  = wide ? (u16*)takeB(NEd * 2) : accB0;

    const int GS = 2048, BS = 256;
    const int RB = (NE + 127) / 128;
    const int NB = (NE + 255) / 256;
    const float inv_ne = 1.f / (float)NE;

    TTab tab;
    int ti = 0;
    for (int l = 0; l < 3; ++l){
        tab.e[ti++] = { cwatt + (size_t)l*2*DD,        wtXatt  + (size_t)l*DD, 128 };
        tab.e[ti++] = { cwatt + (size_t)l*2*DD + DD,   wtScore + (size_t)l*DD, 128 };
        tab.e[ti++] = { cgcn  + (size_t)l*DD,          wtGcn   + (size_t)l*DD, 128 };
    }
    tab.e[ti++] = { al11,       wtAl11,        256 };
    tab.e[ti++] = { al11 + DD,  wtAl11 + 128,  256 };
    tab.e[ti++] = { al12,       wtAl12,        128 };
    tab.e[ti++] = { al21,       wtAl21,        256 };
    tab.e[ti++] = { al21 + DD,  wtAl21 + 128,  256 };
    tab.e[ti++] = { al22,       wtAl22,        128 };
    tab.e[ti++] = { allw,            wtAllw,        384 };
    tab.e[ti++] = { allw + DD,       wtAllw + 128,  384 };
    tab.e[ti++] = { allw + 2*DD,     wtAllw + 256,  384 };
    k_wprep<<<18, 256, 0, stream>>>(tab);

    k_prepz<<<256, BS, 0, stream>>>(zz, ZW, nstart, nend, NB64);
    k_zeroi<<<256, BS, 0, stream>>>((int*)ub0, (int)(NEd/2));
    if (wide) k_zeroi<<<256, BS, 0, stream>>>((int*)ub1, (int)(NEd/2));
    k_f2b4<<<GS, BS, 0, stream>>>(ent_comp, xcb, (int)(NEd/4));
    k_ideg<<<GS, BS, 0, stream>>>(row, ideg, E);
    k_scan1<<<NB, 256, 0, stream>>>(ideg, rowptr, bsum, NE);
    k_scan2<<<1, 256, 0, stream>>>(bsum, NB);
    k_scan3<<<NB, 256, 0, stream>>>(rowptr, bsum, ideg, nstart, nend, NE, E);
    k_scatter<<<GS, BS, 0, stream>>>(row, col, ety, rowptr, cnt, jk, E);

    k_relprep<<<NR + 3*(NR+1), D, 0, stream>>>(rel_comp, rel_info, rl11, rl12,
                                               rl11a, rl12a, cloop, cw1, cw2,
                                               outp + 2*NEd, rel2all, NR);
    k_wgl<<<3, 256, 0, stream>>>(wtGcn, rel2all, NR, wtGcnC);

    // e1 = leaky([l2n(ent_comp), ent_info] @ al11) @ al12
    {
        Srcs S{ ent_comp, ent_info, nullptr, 1, 1, 0 };
        k_mrow<2, 2, true><<<RB, 256, 0, stream>>>(S, wtAl11, hb, NE);
        Srcs S2{ hb, nullptr, nullptr, 0, 0, 0 };
        k_mrow<1, 1, false><<<RB, 256, 0, stream>>>(S2, wtAl12, e1b, NE);
    }

    auto conv_seq = [&](const u16* x, int l, u16* xab, u16* ubp, u16* acb,
                        u16* dstb, float* dstf){
        const float* rel2l = rel2all + (size_t)l*(NR+1)*D;
        float* gp = gp3 + (size_t)l*256;
        XP X{ x, wtXatt + (size_t)l*DD, xab };
        k_xatt2<<<RB, 256, 0, stream>>>(X, X, RB, NE);
        FP fa{ x, rel2l, xab, wtScore + (size_t)l*DD, caatt + (size_t)l*D, ubp };
        k_fedge<<<NB64, 256, 0, stream>>>(jk, rowptr, nstart, nend, fa, fa, NB64);
        GP G{ ubp, x, wtGcnC + (size_t)l*2*DD, acb, gp };
        k_gcn2<<<RB, 256, 0, stream>>>(G, G, RB, NE);
        k_bnapply<<<GS, BS, 0, stream>>>(acb, gp, inv_ne, (int)NEd, dstb, dstf);
    };

    if (wide){
        const float* rel2_0 = rel2all;
        const float* rel2_1 = rel2all + (size_t)(NR+1)*D;
        XP XA{ e1b, wtXatt,      xattb0 };
        XP XB{ xcb, wtXatt + DD, xattb1 };
        k_xatt2<<<2*RB, 256, 0, stream>>>(XA, XB, RB, NE);
        FP fa{ e1b, rel2_0, xattb0, wtScore,      caatt,     ub0 };
        FP fb{ xcb, rel2_1, xattb1, wtScore + DD, caatt + D, ub1 };
        k_fedge<<<2*NB64, 256, 0, stream>>>(jk, rowptr, nstart, nend, fa, fb, NB64);
        GP GA{ ub0, e1b, wtGcnC,          accB0, gp3 };
        GP GB{ ub1, xcb, wtGcnC + 2*DD,   accB1, gp3 + 256 };
        k_gcn2<<<2*RB, 256, 0, stream>>>(GA, GB, RB, NE);
        k_bnapply2<<<2*GS, BS, 0, stream>>>(accB0, gp3, ao1b,
                                            accB1, gp3 + 256, cob, outp + NEd,
                                            inv_ne, (int)NEd, GS);
    } else {
        conv_seq(e1b, 0, xattb0, ub0, accB0, ao1b, nullptr);
        conv_seq(xcb, 1, xattb0, ub0, accB0, cob, outp + NEd);
    }

    // e2 = leaky([l2n(co1), ao1] @ al21) @ al22
    {
        Srcs S{ cob, ao1b, nullptr, 0, 0, 0 };
        k_mrow<2, 2, true><<<RB, 256, 0, stream>>>(S, wtAl21, hb, NE);
        Srcs S2{ hb, nullptr, nullptr, 0, 0, 0 };
        k_mrow<1, 1, false><<<RB, 256, 0, stream>>>(S2, wtAl22, e2b, NE);
    }

    conv_seq(e2b, 2, xattb0, ub0, accB0, cob, nullptr);     // ao2 -> cob

    // out = [e1, ao1, ao2] @ allw -> d_out[0]
    {
        Srcs S{ e1b, ao1b, cob, 0, 0, 0 };
        k_mrow<3, 0, false><<<RB, 256, 0, stream>>>(S, wtAllw, outp, NE);
    }
}